// Round 7
// baseline (125.260 us; speedup 1.0000x reference)
//
#include <hip/hip_runtime.h>
#include <hip/hip_bf16.h>

#define S_SRC 4096
#define DIM 128
#define BATCH 2
#define NQB 64   // 128-row q-blocks
#define NQG 512  // 16-row q-groups total (BATCH*S_SRC/16)

typedef unsigned short u16;
typedef unsigned int u32;
typedef __bf16 bf16x8 __attribute__((ext_vector_type(8)));
typedef float f32x4 __attribute__((ext_vector_type(4)));
typedef u32 u32x4 __attribute__((ext_vector_type(4)));

__device__ __forceinline__ __bf16 bf_hi(float x) { return (__bf16)x; }
__device__ __forceinline__ __bf16 bf_lo(float x, __bf16 h) { return (__bf16)(x - (float)h); }
__device__ __forceinline__ u16 bfu(__bf16 h) { return __builtin_bit_cast(u16, h); }
__device__ __forceinline__ u16 f2bu(float x) { return __builtin_bit_cast(u16, (__bf16)x); }
__device__ __forceinline__ float bu2f(u16 u) { return (float)__builtin_bit_cast(__bf16, u); }
__device__ __forceinline__ u32 pk2(float lo, float hi) {
  return (u32)f2bu(lo) | ((u32)f2bu(hi) << 16);
}
__device__ __forceinline__ void g2l16(const u16* src, u16* ldst) {
  __builtin_amdgcn_global_load_lds((const __attribute__((address_space(1))) void*)src,
                                   (__attribute__((address_space(3))) void*)ldst, 16, 0, 0);
}
#define MFMA __builtin_amdgcn_mfma_f32_16x16x32_bf16

// ---------------- kernel 0: transpose + hi/lo split the weight matrices ----------------
__global__ __launch_bounds__(256) void k_wsplit(const float* __restrict__ wq,
                                                const float* __restrict__ wk,
                                                const float* __restrict__ wv,
                                                u16* __restrict__ wt) {
  int idx = blockIdx.x * 256 + threadIdx.x;  // 3*128*128 = 49152
  int mat = idx >> 14;
  int r = idx & 16383;
  int d = r >> 7, e = r & 127;
  const float* w = (mat == 0) ? wq : ((mat == 1) ? wk : wv);
  float x = w[r];
  if (mat == 0) x *= 0.08838834764831845f;  // fold 1/sqrt(128) into Wq
  __bf16 h = bf_hi(x);
  __bf16 l = bf_lo(x, h);
  wt[((mat * 2 + 0) * 128 + e) * 128 + d] = bfu(h);
  wt[((mat * 2 + 1) * 128 + e) * 128 + d] = bfu(l);
}

// ---------------- kernel 1: QKV projection, one matrix per block ----------------
__global__ __launch_bounds__(256) void k_proj(const float* __restrict__ X,
                                              const u16* __restrict__ wt,
                                              u16* __restrict__ Qh, u16* __restrict__ Ql,
                                              u16* __restrict__ Kh, u16* __restrict__ Kl,
                                              u16* __restrict__ VT) {
  const int mat = blockIdx.x >> 8;
  const int t = blockIdx.x & 255;
  const int b = t >> 7;
  const int tile = t & 127;
  const int tid = threadIdx.x;
  const int w = tid >> 6, lane = tid & 63, g = lane >> 4, l16 = lane & 15;

  bf16x8 a_h[2][4], a_l[2][4];
#pragma unroll
  for (int mf = 0; mf < 2; ++mf) {
    int row = tile * 32 + mf * 16 + l16;
    const float* xr = X + ((size_t)b * S_SRC + row) * DIM;
#pragma unroll
    for (int kf = 0; kf < 4; ++kf) {
      int d0 = kf * 32 + g * 8;
      f32x4 x0 = *(const f32x4*)(xr + d0);
      f32x4 x1 = *(const f32x4*)(xr + d0 + 4);
#pragma unroll
      for (int j = 0; j < 4; ++j) {
        __bf16 h0 = bf_hi(x0[j]);
        __bf16 h1 = bf_hi(x1[j]);
        a_h[mf][kf][j] = h0;
        a_l[mf][kf][j] = bf_lo(x0[j], h0);
        a_h[mf][kf][4 + j] = h1;
        a_l[mf][kf][4 + j] = bf_lo(x1[j], h1);
      }
    }
  }

  const u16* wth = wt + (mat * 2 + 0) * 16384;
  const u16* wtl = wt + (mat * 2 + 1) * 16384;
#pragma unroll
  for (int nf = 0; nf < 2; ++nf) {
    int col = w * 32 + nf * 16 + l16;
    f32x4 acc[2];
    acc[0] = (f32x4){0.f, 0.f, 0.f, 0.f};
    acc[1] = (f32x4){0.f, 0.f, 0.f, 0.f};
#pragma unroll
    for (int kf = 0; kf < 4; ++kf) {
      int d0 = kf * 32 + g * 8;
      bf16x8 bh = *(const bf16x8*)(const void*)(wth + col * 128 + d0);
      bf16x8 bl = *(const bf16x8*)(const void*)(wtl + col * 128 + d0);
#pragma unroll
      for (int mf = 0; mf < 2; ++mf) {
        acc[mf] = MFMA(a_h[mf][kf], bh, acc[mf], 0, 0, 0);
        acc[mf] = MFMA(a_h[mf][kf], bl, acc[mf], 0, 0, 0);
        acc[mf] = MFMA(a_l[mf][kf], bh, acc[mf], 0, 0, 0);
      }
    }
#pragma unroll
    for (int mf = 0; mf < 2; ++mf)
#pragma unroll
      for (int r = 0; r < 4; ++r) {
        int row = tile * 32 + mf * 16 + g * 4 + r;
        float v = acc[mf][r];
        if (mat == 2) {
          VT[((size_t)b * DIM + col) * S_SRC + row] = f2bu(v);
        } else {
          __bf16 h = bf_hi(v);
          __bf16 l = bf_lo(v, h);
          size_t o = ((size_t)b * S_SRC + row) * DIM + col;
          if (mat == 0) { Qh[o] = bfu(h); Ql[o] = bfu(l); }
          else          { Kh[o] = bfu(h); Kl[o] = bfu(l); }
        }
      }
  }
}

// ---------------- kernel 2: flash attention, 4 waves x 32 q-rows, LDS-staged KV ----------------
// Swapped QK^T (A=K, B=Q): lane (g,l16) holds scores of q-col l16 (+16 for qg=1).
__global__ __launch_bounds__(256, 3) void k_attn(const u16* __restrict__ Qh, const u16* __restrict__ Ql,
                                                 const u16* __restrict__ Kh, const u16* __restrict__ Kl,
                                                 const u16* __restrict__ VT,
                                                 float* __restrict__ Pm, float* __restrict__ Pl,
                                                 u16* __restrict__ PO, int nsp) {
  // XCD-aware remap: each XCD gets a contiguous split range (KV -> its L2).
  const int cpx = (NQB * nsp) >> 3;
  const int bid = blockIdx.x;
  const int lid = (bid & 7) * cpx + (bid >> 3);
  const int sp = lid >> 6;   // kv split
  const int qb = lid & 63;   // 128-row q-block
  const int b = qb >> 5;
  const int tid = threadIdx.x;
  const int w = tid >> 6, lane = tid & 63, g = lane >> 4, l16 = lane & 15;

  __shared__ alignas(16) u16 kbuf[2][8192];   // [hi 32x128 | lo 32x128] chunk-swizzled
  __shared__ alignas(16) u16 vbuf[2][4096];   // [128d x 32s] chunk-swizzled

  // ---- Q fragments (hi/lo), 32 q-rows: gr0 .. +31 (2 groups of 16) ----
  const int gr0 = qb * 128 + w * 32;
  bf16x8 q_h[2][4], q_l[2][4];
#pragma unroll
  for (int qg = 0; qg < 2; ++qg) {
    const u16* qph = Qh + ((size_t)gr0 + qg * 16 + l16) * DIM;
    const u16* qpl = Ql + ((size_t)gr0 + qg * 16 + l16) * DIM;
#pragma unroll
    for (int kf = 0; kf < 4; ++kf) {
      int d0 = kf * 32 + g * 8;
      q_h[qg][kf] = *(const bf16x8*)(const void*)(qph + d0);
      q_l[qg][kf] = *(const bf16x8*)(const void*)(qpl + d0);
    }
  }

  f32x4 acc[2][8];
#pragma unroll
  for (int qg = 0; qg < 2; ++qg)
#pragma unroll
    for (int nf = 0; nf < 8; ++nf) acc[qg][nf] = (f32x4){0.f, 0.f, 0.f, 0.f};
  float m0 = -1e30f, m1 = -1e30f, l0 = 0.f, l1 = 0.f;

  const int keys_per = S_SRC / nsp;
  const int key_base = sp * keys_per;
  const int niter = keys_per >> 5;

  const u16* KhB = Kh + (size_t)b * S_SRC * DIM;
  const u16* KlB = Kl + (size_t)b * S_SRC * DIM;
  const u16* VTB = VT + (size_t)b * DIM * S_SRC;

  // staging: 256 threads x 6 chunks of 16B (Khi x2, Klo x2, V x2), chunk-XOR swizzle
  const int kkey = tid >> 4, kcp = tid & 15;
  const int kco = (kcp ^ (kkey & 15)) << 3;
  const int vd = tid >> 2, vcp = tid & 3;
  const int vco = (vcp ^ ((vd >> 1) & 3)) << 3;
  const int wb = w * 512;  // wave-uniform LDS chunk base (u16)

#define STAGE(BUF, KEY0)                                                          \
  {                                                                               \
    g2l16(KhB + ((size_t)((KEY0) + kkey)) * DIM + kco,      &kbuf[BUF][wb]);      \
    g2l16(KhB + ((size_t)((KEY0) + 16 + kkey)) * DIM + kco, &kbuf[BUF][2048 + wb]); \
    g2l16(KlB + ((size_t)((KEY0) + kkey)) * DIM + kco,      &kbuf[BUF][4096 + wb]); \
    g2l16(KlB + ((size_t)((KEY0) + 16 + kkey)) * DIM + kco, &kbuf[BUF][6144 + wb]); \
    g2l16(VTB + (size_t)vd * S_SRC + (KEY0) + vco,          &vbuf[BUF][wb]);      \
    g2l16(VTB + (size_t)(64 + vd) * S_SRC + (KEY0) + vco,   &vbuf[BUF][2048 + wb]); \
  }

  STAGE(0, key_base)

  const int mg = ((g & 1) << 1) | (g >> 1);  // V key-chunk permutation {0,2,1,3}
  int cur = 0;
  for (int i = 0; i < niter; ++i) {
    if (i + 1 < niter) {
      STAGE(cur ^ 1, key_base + (i + 1) * 32)
      asm volatile("s_waitcnt vmcnt(6)" ::: "memory");
    } else {
      asm volatile("s_waitcnt vmcnt(0)" ::: "memory");
    }
    __builtin_amdgcn_s_barrier();

    // ---- QK^T swapped: each K-frag pair feeds both q-groups ----
    const u16* kb = kbuf[cur];
    f32x4 s00, s01, s10, s11;
    s00 = s01 = s10 = s11 = (f32x4){0.f, 0.f, 0.f, 0.f};
    __builtin_amdgcn_s_setprio(1);
#pragma unroll
    for (int kf = 0; kf < 4; ++kf) {
      int cs = ((kf * 4 + g) ^ l16) << 3;
      bf16x8 kh0 = *(const bf16x8*)(const void*)(kb + l16 * 128 + cs);
      bf16x8 kl0 = *(const bf16x8*)(const void*)(kb + 4096 + l16 * 128 + cs);
      s00 = MFMA(kh0, q_h[0][kf], s00, 0, 0, 0);
      s00 = MFMA(kh0, q_l[0][kf], s00, 0, 0, 0);
      s00 = MFMA(kl0, q_h[0][kf], s00, 0, 0, 0);
      s10 = MFMA(kh0, q_h[1][kf], s10, 0, 0, 0);
      s10 = MFMA(kh0, q_l[1][kf], s10, 0, 0, 0);
      s10 = MFMA(kl0, q_h[1][kf], s10, 0, 0, 0);
      bf16x8 kh1 = *(const bf16x8*)(const void*)(kb + (16 + l16) * 128 + cs);
      bf16x8 kl1 = *(const bf16x8*)(const void*)(kb + 4096 + (16 + l16) * 128 + cs);
      s01 = MFMA(kh1, q_h[0][kf], s01, 0, 0, 0);
      s01 = MFMA(kh1, q_l[0][kf], s01, 0, 0, 0);
      s01 = MFMA(kl1, q_h[0][kf], s01, 0, 0, 0);
      s11 = MFMA(kh1, q_h[1][kf], s11, 0, 0, 0);
      s11 = MFMA(kh1, q_l[1][kf], s11, 0, 0, 0);
      s11 = MFMA(kl1, q_h[1][kf], s11, 0, 0, 0);
    }
    __builtin_amdgcn_s_setprio(0);

    // ---- softmax + P-pack per q-group (lane-local rows, 2 shfl reduces) ----
    bf16x8 pa0, pa1;
#pragma unroll
    for (int qg = 0; qg < 2; ++qg) {
      f32x4 sA = qg ? s10 : s00;
      f32x4 sB = qg ? s11 : s01;
      float mr = qg ? m1 : m0;
      float lr = qg ? l1 : l0;
      float mx = fmaxf(fmaxf(fmaxf(sA[0], sA[1]), fmaxf(sA[2], sA[3])),
                       fmaxf(fmaxf(sB[0], sB[1]), fmaxf(sB[2], sB[3])));
      mx = fmaxf(mx, __shfl_xor(mx, 16, 64));
      mx = fmaxf(mx, __shfl_xor(mx, 32, 64));
      if (!__all(mx - mr <= 8.0f)) {  // defer-rescale (exact math either way)
        float mn = fmaxf(mr, mx);
        float f = __expf(mr - mn);
        lr *= f;
        mr = mn;
        float fr0 = __shfl(f, g * 4 + 0, 64);
        float fr1 = __shfl(f, g * 4 + 1, 64);
        float fr2 = __shfl(f, g * 4 + 2, 64);
        float fr3 = __shfl(f, g * 4 + 3, 64);
        if (qg == 0) {
#pragma unroll
          for (int nf = 0; nf < 8; ++nf) {
            acc[0][nf][0] *= fr0; acc[0][nf][1] *= fr1;
            acc[0][nf][2] *= fr2; acc[0][nf][3] *= fr3;
          }
        } else {
#pragma unroll
          for (int nf = 0; nf < 8; ++nf) {
            acc[1][nf][0] *= fr0; acc[1][nf][1] *= fr1;
            acc[1][nf][2] *= fr2; acc[1][nf][3] *= fr3;
          }
        }
      }
      float e0 = __expf(sA[0] - mr), e1 = __expf(sA[1] - mr);
      float e2 = __expf(sA[2] - mr), e3 = __expf(sA[3] - mr);
      float e4 = __expf(sB[0] - mr), e5 = __expf(sB[1] - mr);
      float e6 = __expf(sB[2] - mr), e7 = __expf(sB[3] - mr);
      float sm = ((e0 + e1) + (e2 + e3)) + ((e4 + e5) + (e6 + e7));
      sm += __shfl_xor(sm, 16, 64);
      sm += __shfl_xor(sm, 32, 64);
      lr += sm;
      if (qg == 0) { m0 = mr; l0 = lr; } else { m1 = mr; l1 = lr; }

      u32 w0 = pk2(e0, e1), w1 = pk2(e2, e3), w2 = pk2(e4, e5), w3 = pk2(e6, e7);
      u32 x0 = __shfl_xor(w0, 16, 64), x1 = __shfl_xor(w1, 16, 64);
      u32 x2 = __shfl_xor(w2, 16, 64), x3 = __shfl_xor(w3, 16, 64);
      bool odd = (g & 1);
      u32x4 pw;
      pw.x = odd ? x2 : w0;
      pw.y = odd ? x3 : w1;
      pw.z = odd ? w2 : x0;
      pw.w = odd ? w3 : x1;
      if (qg == 0) pa0 = __builtin_bit_cast(bf16x8, pw);
      else         pa1 = __builtin_bit_cast(bf16x8, pw);
    }

    // ---- PV: one V-frag read feeds both q-groups ----
    const u16* vb = vbuf[cur];
    __builtin_amdgcn_s_setprio(1);
#pragma unroll
    for (int nf = 0; nf < 8; ++nf) {
      int d = nf * 16 + l16;
      bf16x8 vf = *(const bf16x8*)(const void*)(vb + d * 32 + ((mg ^ ((d >> 1) & 3)) << 3));
      acc[0][nf] = MFMA(pa0, vf, acc[0][nf], 0, 0, 0);
      acc[1][nf] = MFMA(pa1, vf, acc[1][nf], 0, 0, 0);
    }
    __builtin_amdgcn_s_setprio(0);

    __builtin_amdgcn_s_barrier();
    cur ^= 1;
  }

  // ---- write partials (m, l, O) for the 2 16-row groups ----
  const int pidx0 = sp * NQG + (gr0 >> 4);
#pragma unroll
  for (int qg = 0; qg < 2; ++qg) {
    u16* po = PO + (size_t)(pidx0 + qg) * 16 * DIM;
#pragma unroll
    for (int nf = 0; nf < 8; ++nf)
#pragma unroll
      for (int r = 0; r < 4; ++r)
        po[(g * 4 + r) * DIM + nf * 16 + l16] = f2bu(acc[qg][nf][r]);
  }
  if (g == 0) { Pm[pidx0 * 16 + l16] = m0; Pl[pidx0 * 16 + l16] = l0; }
  if (g == 1) { Pm[(pidx0 + 1) * 16 + l16] = m1; Pl[(pidx0 + 1) * 16 + l16] = l1; }
#undef STAGE
}

// ---------------- kernel 3: combine KV-split partials ----------------
__global__ __launch_bounds__(64) void k_comb(const float* __restrict__ Pm,
                                             const float* __restrict__ Pl,
                                             const u16* __restrict__ PO,
                                             float* __restrict__ out, int nsp) {
  const int qg = blockIdx.x;
  const int tid = threadIdx.x;

  __shared__ float sc[16][16];  // [split][row]
  if (tid < 16) {
    float m = -1e30f;
    for (int s = 0; s < nsp; ++s) m = fmaxf(m, Pm[(s * NQG + qg) * 16 + tid]);
    float den = 0.f;
    for (int s = 0; s < nsp; ++s) {
      float e = __expf(Pm[(s * NQG + qg) * 16 + tid] - m);
      sc[s][tid] = e;
      den += Pl[(s * NQG + qg) * 16 + tid] * e;
    }
    float inv = 1.0f / den;
    for (int s = 0; s < nsp; ++s) sc[s][tid] *= inv;
  }
  __syncthreads();

  float* op = out + (size_t)qg * 16 * DIM;
  for (int i = tid; i < 16 * DIM; i += 64) {
    int row = i >> 7;
    float a = 0.f;
    for (int s = 0; s < nsp; ++s)
      a += bu2f(PO[(size_t)(s * NQG + qg) * 16 * DIM + i]) * sc[s][row];
    op[i] = a;
  }
}

extern "C" void kernel_launch(void* const* d_in, const int* in_sizes, int n_in,
                              void* d_out, int out_size, void* d_ws, size_t ws_size,
                              hipStream_t stream) {
  const float* X  = (const float*)d_in[0];
  const float* wq = (const float*)d_in[4];
  const float* wk = (const float*)d_in[5];
  const float* wv = (const float*)d_in[6];
  float* out = (float*)d_out;

  u16* WT = (u16*)d_ws;                       // 3*2*128*128 u16 = 192 KiB
  u16* Qh = WT + 3 * 2 * 128 * 128;
  u16* Ql = Qh + (size_t)BATCH * S_SRC * DIM; // 2 MiB each
  u16* Kh = Ql + (size_t)BATCH * S_SRC * DIM;
  u16* Kl = Kh + (size_t)BATCH * S_SRC * DIM;
  u16* VT = Kl + (size_t)BATCH * S_SRC * DIM; // [B][D][S]

  // pick split count by workspace budget (deterministic: ws_size is fixed)
  size_t fixed_b = (size_t)(3 * 2 * 128 * 128) * 2 + (size_t)5 * BATCH * S_SRC * DIM * 2;
  int nsp = 16;
  size_t need = fixed_b + (size_t)nsp * NQG * 16 * 8 + (size_t)nsp * NQG * 16 * DIM * 2;
  if (ws_size < need) nsp = 8;

  float* Pm = (float*)(VT + (size_t)BATCH * S_SRC * DIM);  // [nsp*NQG*16] f32
  float* Pl = Pm + (size_t)nsp * NQG * 16;
  u16* PO = (u16*)(Pl + (size_t)nsp * NQG * 16);           // [nsp*NQG*16*128] bf16

  hipLaunchKernelGGL(k_wsplit, dim3(192), dim3(256), 0, stream, wq, wk, wv, WT);
  hipLaunchKernelGGL(k_proj, dim3(3 * 256), dim3(256), 0, stream,
                     X, WT, Qh, Ql, Kh, Kl, VT);
  hipLaunchKernelGGL(k_attn, dim3(NQB * nsp), dim3(256), 0, stream,
                     Qh, Ql, Kh, Kl, VT, Pm, Pl, PO, nsp);
  hipLaunchKernelGGL(k_comb, dim3(NQG), dim3(64), 0, stream, Pm, Pl, PO, out, nsp);
}

// Round 8
// 80.454 us; speedup vs baseline: 1.5569x; 1.5569x over previous
//
#include <hip/hip_runtime.h>
#include <hip/hip_bf16.h>

#define S_SRC 4096
#define DIM 128
#define BATCH 2
#define NSP 8
#define NQB 32   // 256-row q-blocks
#define NQG 512  // 16-row q-groups total (BATCH*S_SRC/16)

typedef unsigned short u16;
typedef unsigned int u32;
typedef __bf16 bf16x8 __attribute__((ext_vector_type(8)));
typedef float f32x4 __attribute__((ext_vector_type(4)));
typedef u32 u32x4 __attribute__((ext_vector_type(4)));

__device__ __forceinline__ __bf16 bf_hi(float x) { return (__bf16)x; }
__device__ __forceinline__ __bf16 bf_lo(float x, __bf16 h) { return (__bf16)(x - (float)h); }
__device__ __forceinline__ u16 bfu(__bf16 h) { return __builtin_bit_cast(u16, h); }
__device__ __forceinline__ u16 f2bu(float x) { return __builtin_bit_cast(u16, (__bf16)x); }
__device__ __forceinline__ float bu2f(u16 u) { return (float)__builtin_bit_cast(__bf16, u); }
__device__ __forceinline__ u32 pk2(float lo, float hi) {
  return (u32)f2bu(lo) | ((u32)f2bu(hi) << 16);
}
__device__ __forceinline__ void g2l16(const u16* src, u16* ldst) {
  __builtin_amdgcn_global_load_lds((const __attribute__((address_space(1))) void*)src,
                                   (__attribute__((address_space(3))) void*)ldst, 16, 0, 0);
}
#define MFMA __builtin_amdgcn_mfma_f32_16x16x32_bf16

// ---------------- kernel 0: transpose + hi/lo split the weight matrices ----------------
__global__ __launch_bounds__(256) void k_wsplit(const float* __restrict__ wq,
                                                const float* __restrict__ wk,
                                                const float* __restrict__ wv,
                                                u16* __restrict__ wt) {
  int idx = blockIdx.x * 256 + threadIdx.x;  // 3*128*128 = 49152
  int mat = idx >> 14;
  int r = idx & 16383;
  int d = r >> 7, e = r & 127;
  const float* w = (mat == 0) ? wq : ((mat == 1) ? wk : wv);
  float x = w[r];
  if (mat == 0) x *= 0.08838834764831845f;  // fold 1/sqrt(128) into Wq
  __bf16 h = bf_hi(x);
  __bf16 l = bf_lo(x, h);
  wt[((mat * 2 + 0) * 128 + e) * 128 + d] = bfu(h);
  wt[((mat * 2 + 1) * 128 + e) * 128 + d] = bfu(l);
}

// ---------------- kernel 1: QKV projection, one matrix per block ----------------
__global__ __launch_bounds__(256) void k_proj(const float* __restrict__ X,
                                              const u16* __restrict__ wt,
                                              u16* __restrict__ Qh, u16* __restrict__ Ql,
                                              u16* __restrict__ Kh, u16* __restrict__ Kl,
                                              u16* __restrict__ VT) {
  const int mat = blockIdx.x >> 8;
  const int t = blockIdx.x & 255;
  const int b = t >> 7;
  const int tile = t & 127;
  const int tid = threadIdx.x;
  const int w = tid >> 6, lane = tid & 63, g = lane >> 4, l16 = lane & 15;

  bf16x8 a_h[2][4], a_l[2][4];
#pragma unroll
  for (int mf = 0; mf < 2; ++mf) {
    int row = tile * 32 + mf * 16 + l16;
    const float* xr = X + ((size_t)b * S_SRC + row) * DIM;
#pragma unroll
    for (int kf = 0; kf < 4; ++kf) {
      int d0 = kf * 32 + g * 8;
      f32x4 x0 = *(const f32x4*)(xr + d0);
      f32x4 x1 = *(const f32x4*)(xr + d0 + 4);
#pragma unroll
      for (int j = 0; j < 4; ++j) {
        __bf16 h0 = bf_hi(x0[j]);
        __bf16 h1 = bf_hi(x1[j]);
        a_h[mf][kf][j] = h0;
        a_l[mf][kf][j] = bf_lo(x0[j], h0);
        a_h[mf][kf][4 + j] = h1;
        a_l[mf][kf][4 + j] = bf_lo(x1[j], h1);
      }
    }
  }

  const u16* wth = wt + (mat * 2 + 0) * 16384;
  const u16* wtl = wt + (mat * 2 + 1) * 16384;
#pragma unroll
  for (int nf = 0; nf < 2; ++nf) {
    int col = w * 32 + nf * 16 + l16;
    f32x4 acc[2];
    acc[0] = (f32x4){0.f, 0.f, 0.f, 0.f};
    acc[1] = (f32x4){0.f, 0.f, 0.f, 0.f};
#pragma unroll
    for (int kf = 0; kf < 4; ++kf) {
      int d0 = kf * 32 + g * 8;
      bf16x8 bh = *(const bf16x8*)(const void*)(wth + col * 128 + d0);
      bf16x8 bl = *(const bf16x8*)(const void*)(wtl + col * 128 + d0);
#pragma unroll
      for (int mf = 0; mf < 2; ++mf) {
        acc[mf] = MFMA(a_h[mf][kf], bh, acc[mf], 0, 0, 0);
        acc[mf] = MFMA(a_h[mf][kf], bl, acc[mf], 0, 0, 0);
        acc[mf] = MFMA(a_l[mf][kf], bh, acc[mf], 0, 0, 0);
      }
    }
#pragma unroll
    for (int mf = 0; mf < 2; ++mf)
#pragma unroll
      for (int r = 0; r < 4; ++r) {
        int row = tile * 32 + mf * 16 + g * 4 + r;
        float v = acc[mf][r];
        if (mat == 2) {
          VT[((size_t)b * DIM + col) * S_SRC + row] = f2bu(v);
        } else {
          __bf16 h = bf_hi(v);
          __bf16 l = bf_lo(v, h);
          size_t o = ((size_t)b * S_SRC + row) * DIM + col;
          if (mat == 0) { Qh[o] = bfu(h); Ql[o] = bfu(l); }
          else          { Kh[o] = bfu(h); Kl[o] = bfu(l); }
        }
      }
  }
}

// ---------------- kernel 2: flash attention, 8 waves x 32 q-rows, LDS-staged KV ----------------
// Swapped QK^T (A=K, B=Q): lane (g,l16) holds scores of q-col l16 of each 16-row group.
__global__ __launch_bounds__(512, 2) void k_attn(const u16* __restrict__ Qh, const u16* __restrict__ Ql,
                                                 const u16* __restrict__ Kh, const u16* __restrict__ Kl,
                                                 const u16* __restrict__ VT,
                                                 float* __restrict__ Pm, float* __restrict__ Pl,
                                                 u16* __restrict__ PO) {
  // XCD-aware remap: 256 blocks = 8 XCDs x 32. XCD x gets split x (its KV panel -> its L2).
  const int bid = blockIdx.x;
  const int sp = bid & 7;     // kv split 0..7
  const int qb = bid >> 3;    // 256-row q-block 0..31
  const int b = qb >> 4;
  const int tid = threadIdx.x;
  const int w = tid >> 6, lane = tid & 63, g = lane >> 4, l16 = lane & 15;

  __shared__ alignas(16) u16 kbuf[2][8192];   // [hi 32x128 | lo 32x128] chunk-swizzled
  __shared__ alignas(16) u16 vbuf[2][4096];   // [128d x 32s] chunk-swizzled

  // ---- Q fragments (hi/lo), 32 q-rows: gr0 .. +31 (2 groups of 16) ----
  const int gr0 = qb * 256 + w * 32;
  bf16x8 q_h[2][4], q_l[2][4];
#pragma unroll
  for (int qg = 0; qg < 2; ++qg) {
    const u16* qph = Qh + ((size_t)gr0 + qg * 16 + l16) * DIM;
    const u16* qpl = Ql + ((size_t)gr0 + qg * 16 + l16) * DIM;
#pragma unroll
    for (int kf = 0; kf < 4; ++kf) {
      int d0 = kf * 32 + g * 8;
      q_h[qg][kf] = *(const bf16x8*)(const void*)(qph + d0);
      q_l[qg][kf] = *(const bf16x8*)(const void*)(qpl + d0);
    }
  }

  f32x4 acc[2][8];
#pragma unroll
  for (int qg = 0; qg < 2; ++qg)
#pragma unroll
    for (int nf = 0; nf < 8; ++nf) acc[qg][nf] = (f32x4){0.f, 0.f, 0.f, 0.f};
  float m0 = -1e30f, m1 = -1e30f, l0 = 0.f, l1 = 0.f;

  const int keys_per = S_SRC / NSP;
  const int key_base = sp * keys_per;
  const int niter = keys_per >> 5;

  const u16* KhB = Kh + (size_t)b * S_SRC * DIM;
  const u16* KlB = Kl + (size_t)b * S_SRC * DIM;
  const u16* VTB = VT + (size_t)b * DIM * S_SRC;

  // staging (512 threads x 3 chunks of 16B), chunk-XOR swizzle
  const int kkey = tid >> 4, kcp = tid & 15;                 // K chunk (key, slot)
  const int kcs = (kcp ^ (kkey & 15)) << 3;                  // source d-offset (elems)
  const int vd = tid >> 2, vcp = tid & 3;                    // V chunk (d, slot)
  const int vcs = (vcp ^ ((vd >> 1) & 3)) << 3;              // source s-offset (elems)
  const int wbase = w * 512;                                 // wave-uniform LDS chunk base (u16)

#define STAGE(BUF, KEY0)                                                        \
  {                                                                             \
    g2l16(KhB + ((size_t)((KEY0) + kkey)) * DIM + kcs, &kbuf[BUF][wbase]);      \
    g2l16(KlB + ((size_t)((KEY0) + kkey)) * DIM + kcs, &kbuf[BUF][4096 + wbase]); \
    g2l16(VTB + (size_t)vd * S_SRC + (KEY0) + vcs,     &vbuf[BUF][wbase]);      \
  }

  STAGE(0, key_base)

  const int mg = ((g & 1) << 1) | (g >> 1);  // V key-chunk permutation {0,2,1,3}
  int cur = 0;
  for (int i = 0; i < niter; ++i) {
    if (i + 1 < niter) {
      STAGE(cur ^ 1, key_base + (i + 1) * 32)
      asm volatile("s_waitcnt vmcnt(3)" ::: "memory");
    } else {
      asm volatile("s_waitcnt vmcnt(0)" ::: "memory");
    }
    __builtin_amdgcn_s_barrier();

    // ---- QK^T swapped: each K-frag read feeds both q-groups ----
    const u16* kb = kbuf[cur];
    f32x4 s00, s01, s10, s11;
    s00 = s01 = s10 = s11 = (f32x4){0.f, 0.f, 0.f, 0.f};
    __builtin_amdgcn_s_setprio(1);
#pragma unroll
    for (int kf = 0; kf < 4; ++kf) {
      int cs = ((kf * 4 + g) ^ l16) << 3;
      bf16x8 kh0 = *(const bf16x8*)(const void*)(kb + l16 * 128 + cs);
      bf16x8 kl0 = *(const bf16x8*)(const void*)(kb + 4096 + l16 * 128 + cs);
      s00 = MFMA(kh0, q_h[0][kf], s00, 0, 0, 0);
      s00 = MFMA(kh0, q_l[0][kf], s00, 0, 0, 0);
      s00 = MFMA(kl0, q_h[0][kf], s00, 0, 0, 0);
      s10 = MFMA(kh0, q_h[1][kf], s10, 0, 0, 0);
      s10 = MFMA(kh0, q_l[1][kf], s10, 0, 0, 0);
      s10 = MFMA(kl0, q_h[1][kf], s10, 0, 0, 0);
      bf16x8 kh1 = *(const bf16x8*)(const void*)(kb + (16 + l16) * 128 + cs);
      bf16x8 kl1 = *(const bf16x8*)(const void*)(kb + 4096 + (16 + l16) * 128 + cs);
      s01 = MFMA(kh1, q_h[0][kf], s01, 0, 0, 0);
      s01 = MFMA(kh1, q_l[0][kf], s01, 0, 0, 0);
      s01 = MFMA(kl1, q_h[0][kf], s01, 0, 0, 0);
      s11 = MFMA(kh1, q_h[1][kf], s11, 0, 0, 0);
      s11 = MFMA(kh1, q_l[1][kf], s11, 0, 0, 0);
      s11 = MFMA(kl1, q_h[1][kf], s11, 0, 0, 0);
    }
    __builtin_amdgcn_s_setprio(0);

    // ---- softmax + P-pack per q-group (lane-local rows, 2 shfl reduces) ----
    bf16x8 pa0, pa1;
#pragma unroll
    for (int qg = 0; qg < 2; ++qg) {
      f32x4 sA = qg ? s10 : s00;
      f32x4 sB = qg ? s11 : s01;
      float mr = qg ? m1 : m0;
      float lr = qg ? l1 : l0;
      float mx = fmaxf(fmaxf(fmaxf(sA[0], sA[1]), fmaxf(sA[2], sA[3])),
                       fmaxf(fmaxf(sB[0], sB[1]), fmaxf(sB[2], sB[3])));
      mx = fmaxf(mx, __shfl_xor(mx, 16, 64));
      mx = fmaxf(mx, __shfl_xor(mx, 32, 64));
      if (!__all(mx - mr <= 8.0f)) {  // defer-rescale (exact math either way)
        float mn = fmaxf(mr, mx);
        float f = __expf(mr - mn);
        lr *= f;
        mr = mn;
        float fr0 = __shfl(f, g * 4 + 0, 64);
        float fr1 = __shfl(f, g * 4 + 1, 64);
        float fr2 = __shfl(f, g * 4 + 2, 64);
        float fr3 = __shfl(f, g * 4 + 3, 64);
        if (qg == 0) {
#pragma unroll
          for (int nf = 0; nf < 8; ++nf) {
            acc[0][nf][0] *= fr0; acc[0][nf][1] *= fr1;
            acc[0][nf][2] *= fr2; acc[0][nf][3] *= fr3;
          }
        } else {
#pragma unroll
          for (int nf = 0; nf < 8; ++nf) {
            acc[1][nf][0] *= fr0; acc[1][nf][1] *= fr1;
            acc[1][nf][2] *= fr2; acc[1][nf][3] *= fr3;
          }
        }
      }
      float e0 = __expf(sA[0] - mr), e1 = __expf(sA[1] - mr);
      float e2 = __expf(sA[2] - mr), e3 = __expf(sA[3] - mr);
      float e4 = __expf(sB[0] - mr), e5 = __expf(sB[1] - mr);
      float e6 = __expf(sB[2] - mr), e7 = __expf(sB[3] - mr);
      float sm = ((e0 + e1) + (e2 + e3)) + ((e4 + e5) + (e6 + e7));
      sm += __shfl_xor(sm, 16, 64);
      sm += __shfl_xor(sm, 32, 64);
      lr += sm;
      if (qg == 0) { m0 = mr; l0 = lr; } else { m1 = mr; l1 = lr; }

      u32 w0 = pk2(e0, e1), w1 = pk2(e2, e3), w2 = pk2(e4, e5), w3 = pk2(e6, e7);
      u32 x0 = __shfl_xor(w0, 16, 64), x1 = __shfl_xor(w1, 16, 64);
      u32 x2 = __shfl_xor(w2, 16, 64), x3 = __shfl_xor(w3, 16, 64);
      bool odd = (g & 1);
      u32x4 pw;
      pw.x = odd ? x2 : w0;
      pw.y = odd ? x3 : w1;
      pw.z = odd ? w2 : x0;
      pw.w = odd ? w3 : x1;
      if (qg == 0) pa0 = __builtin_bit_cast(bf16x8, pw);
      else         pa1 = __builtin_bit_cast(bf16x8, pw);
    }

    // ---- PV: one V-frag read feeds both q-groups ----
    const u16* vb = vbuf[cur];
    __builtin_amdgcn_s_setprio(1);
#pragma unroll
    for (int nf = 0; nf < 8; ++nf) {
      int d = nf * 16 + l16;
      bf16x8 vf = *(const bf16x8*)(const void*)(vb + d * 32 + ((mg ^ ((d >> 1) & 3)) << 3));
      acc[0][nf] = MFMA(pa0, vf, acc[0][nf], 0, 0, 0);
      acc[1][nf] = MFMA(pa1, vf, acc[1][nf], 0, 0, 0);
    }
    __builtin_amdgcn_s_setprio(0);

    __builtin_amdgcn_s_barrier();
    cur ^= 1;
  }

  // ---- write partials (m, l, O) for the 2 16-row groups ----
  const int pidx0 = sp * NQG + (gr0 >> 4);
#pragma unroll
  for (int qg = 0; qg < 2; ++qg) {
    u16* po = PO + (size_t)(pidx0 + qg) * 16 * DIM;
#pragma unroll
    for (int nf = 0; nf < 8; ++nf)
#pragma unroll
      for (int r = 0; r < 4; ++r)
        po[(g * 4 + r) * DIM + nf * 16 + l16] = f2bu(acc[qg][nf][r]);
  }
  if (g == 0) { Pm[pidx0 * 16 + l16] = m0; Pl[pidx0 * 16 + l16] = l0; }
  if (g == 1) { Pm[(pidx0 + 1) * 16 + l16] = m1; Pl[(pidx0 + 1) * 16 + l16] = l1; }
#undef STAGE
}

// ---------------- kernel 3: combine KV-split partials ----------------
__global__ __launch_bounds__(64) void k_comb(const float* __restrict__ Pm,
                                             const float* __restrict__ Pl,
                                             const u16* __restrict__ PO,
                                             float* __restrict__ out) {
  const int qg = blockIdx.x;
  const int tid = threadIdx.x;

  __shared__ float sc[NSP][16];  // [split][row]
  if (tid < 16) {
    float m = -1e30f;
#pragma unroll
    for (int s = 0; s < NSP; ++s) m = fmaxf(m, Pm[(s * NQG + qg) * 16 + tid]);
    float den = 0.f;
#pragma unroll
    for (int s = 0; s < NSP; ++s) {
      float e = __expf(Pm[(s * NQG + qg) * 16 + tid] - m);
      sc[s][tid] = e;
      den += Pl[(s * NQG + qg) * 16 + tid] * e;
    }
    float inv = 1.0f / den;
#pragma unroll
    for (int s = 0; s < NSP; ++s) sc[s][tid] *= inv;
  }
  __syncthreads();

  float* op = out + (size_t)qg * 16 * DIM;
  for (int i = tid; i < 16 * DIM; i += 64) {
    int row = i >> 7;
    float a = 0.f;
#pragma unroll
    for (int s = 0; s < NSP; ++s)
      a += bu2f(PO[(size_t)(s * NQG + qg) * 16 * DIM + i]) * sc[s][row];
    op[i] = a;
  }
}

extern "C" void kernel_launch(void* const* d_in, const int* in_sizes, int n_in,
                              void* d_out, int out_size, void* d_ws, size_t ws_size,
                              hipStream_t stream) {
  const float* X  = (const float*)d_in[0];
  const float* wq = (const float*)d_in[4];
  const float* wk = (const float*)d_in[5];
  const float* wv = (const float*)d_in[6];
  float* out = (float*)d_out;

  u16* WT = (u16*)d_ws;                       // 3*2*128*128 u16 = 192 KiB
  u16* Qh = WT + 3 * 2 * 128 * 128;
  u16* Ql = Qh + (size_t)BATCH * S_SRC * DIM; // 2 MiB each
  u16* Kh = Ql + (size_t)BATCH * S_SRC * DIM;
  u16* Kl = Kh + (size_t)BATCH * S_SRC * DIM;
  u16* VT = Kl + (size_t)BATCH * S_SRC * DIM; // [B][D][S]
  float* Pm = (float*)(VT + (size_t)BATCH * S_SRC * DIM);  // [NSP*NQG*16] f32
  float* Pl = Pm + (size_t)NSP * NQG * 16;
  u16* PO = (u16*)(Pl + (size_t)NSP * NQG * 16);           // [NSP*NQG*16*128] bf16 = 16 MiB

  hipLaunchKernelGGL(k_wsplit, dim3(192), dim3(256), 0, stream, wq, wk, wv, WT);
  hipLaunchKernelGGL(k_proj, dim3(3 * 256), dim3(256), 0, stream,
                     X, WT, Qh, Ql, Kh, Kl, VT);
  hipLaunchKernelGGL(k_attn, dim3(NQB * NSP), dim3(512), 0, stream,
                     Qh, Ql, Kh, Kl, VT, Pm, Pl, PO);
  hipLaunchKernelGGL(k_comb, dim3(NQG), dim3(64), 0, stream, Pm, Pl, PO, out);
}

// Round 9
// 75.202 us; speedup vs baseline: 1.6657x; 1.0698x over previous
//
#include <hip/hip_runtime.h>
#include <hip/hip_bf16.h>

#define S_SRC 4096
#define DIM 128
#define BATCH 2
#define NSP 8
#define NQB 32    // 256-row q-blocks
#define NQG 512   // 16-row q-groups total
#define NITER 16  // (S_SRC/NSP)/32 key tiles per split

typedef unsigned short u16;
typedef unsigned int u32;
typedef __bf16 bf16x8 __attribute__((ext_vector_type(8)));
typedef float f32x4 __attribute__((ext_vector_type(4)));
typedef u32 u32x4 __attribute__((ext_vector_type(4)));
typedef u16 u16x4 __attribute__((ext_vector_type(4)));

__device__ __forceinline__ __bf16 bf_hi(float x) { return (__bf16)x; }
__device__ __forceinline__ __bf16 bf_lo(float x, __bf16 h) { return (__bf16)(x - (float)h); }
__device__ __forceinline__ u16 bfu(__bf16 h) { return __builtin_bit_cast(u16, h); }
__device__ __forceinline__ u16 f2bu(float x) { return __builtin_bit_cast(u16, (__bf16)x); }
__device__ __forceinline__ float bu2f(u16 u) { return (float)__builtin_bit_cast(__bf16, u); }
__device__ __forceinline__ u32 pk2(float lo, float hi) {
  return (u32)f2bu(lo) | ((u32)f2bu(hi) << 16);
}
__device__ __forceinline__ void g2l16(const u16* src, u16* ldst) {
  __builtin_amdgcn_global_load_lds((const __attribute__((address_space(1))) void*)src,
                                   (__attribute__((address_space(3))) void*)ldst, 16, 0, 0);
}
#define MFMA __builtin_amdgcn_mfma_f32_16x16x32_bf16

// ---------------- kernel 0: transpose + hi/lo split the weight matrices ----------------
__global__ __launch_bounds__(256) void k_wsplit(const float* __restrict__ wq,
                                                const float* __restrict__ wk,
                                                const float* __restrict__ wv,
                                                u16* __restrict__ wt) {
  int idx = blockIdx.x * 256 + threadIdx.x;  // 3*128*128 = 49152
  int mat = idx >> 14;
  int r = idx & 16383;
  int d = r >> 7, e = r & 127;
  const float* w = (mat == 0) ? wq : ((mat == 1) ? wk : wv);
  float x = w[r];
  if (mat == 0) x *= 0.08838834764831845f;  // fold 1/sqrt(128) into Wq
  __bf16 h = bf_hi(x);
  __bf16 l = bf_lo(x, h);
  wt[((mat * 2 + 0) * 128 + e) * 128 + d] = bfu(h);
  wt[((mat * 2 + 1) * 128 + e) * 128 + d] = bfu(l);
}

// ---------------- kernel 1: QKV projection, one matrix per block ----------------
__global__ __launch_bounds__(256) void k_proj(const float* __restrict__ X,
                                              const u16* __restrict__ wt,
                                              u16* __restrict__ Qh, u16* __restrict__ Ql,
                                              u16* __restrict__ Kh, u16* __restrict__ Kl,
                                              u16* __restrict__ VT) {
  const int mat = blockIdx.x >> 8;
  const int t = blockIdx.x & 255;
  const int b = t >> 7;
  const int tile = t & 127;
  const int tid = threadIdx.x;
  const int w = tid >> 6, lane = tid & 63, g = lane >> 4, l16 = lane & 15;

  bf16x8 a_h[2][4], a_l[2][4];
#pragma unroll
  for (int mf = 0; mf < 2; ++mf) {
    int row = tile * 32 + mf * 16 + l16;
    const float* xr = X + ((size_t)b * S_SRC + row) * DIM;
#pragma unroll
    for (int kf = 0; kf < 4; ++kf) {
      int d0 = kf * 32 + g * 8;
      f32x4 x0 = *(const f32x4*)(xr + d0);
      f32x4 x1 = *(const f32x4*)(xr + d0 + 4);
#pragma unroll
      for (int j = 0; j < 4; ++j) {
        __bf16 h0 = bf_hi(x0[j]);
        __bf16 h1 = bf_hi(x1[j]);
        a_h[mf][kf][j] = h0;
        a_l[mf][kf][j] = bf_lo(x0[j], h0);
        a_h[mf][kf][4 + j] = h1;
        a_l[mf][kf][4 + j] = bf_lo(x1[j], h1);
      }
    }
  }

  const u16* wth = wt + (mat * 2 + 0) * 16384;
  const u16* wtl = wt + (mat * 2 + 1) * 16384;
#pragma unroll
  for (int nf = 0; nf < 2; ++nf) {
    int col = w * 32 + nf * 16 + l16;
    f32x4 acc[2];
    acc[0] = (f32x4){0.f, 0.f, 0.f, 0.f};
    acc[1] = (f32x4){0.f, 0.f, 0.f, 0.f};
#pragma unroll
    for (int kf = 0; kf < 4; ++kf) {
      int d0 = kf * 32 + g * 8;
      bf16x8 bh = *(const bf16x8*)(const void*)(wth + col * 128 + d0);
      bf16x8 bl = *(const bf16x8*)(const void*)(wtl + col * 128 + d0);
#pragma unroll
      for (int mf = 0; mf < 2; ++mf) {
        acc[mf] = MFMA(a_h[mf][kf], bh, acc[mf], 0, 0, 0);
        acc[mf] = MFMA(a_h[mf][kf], bl, acc[mf], 0, 0, 0);
        acc[mf] = MFMA(a_l[mf][kf], bh, acc[mf], 0, 0, 0);
      }
    }
#pragma unroll
    for (int mf = 0; mf < 2; ++mf)
#pragma unroll
      for (int r = 0; r < 4; ++r) {
        int row = tile * 32 + mf * 16 + g * 4 + r;
        float v = acc[mf][r];
        if (mat == 2) {
          VT[((size_t)b * DIM + col) * S_SRC + row] = f2bu(v);
        } else {
          __bf16 h = bf_hi(v);
          __bf16 l = bf_lo(v, h);
          size_t o = ((size_t)b * S_SRC + row) * DIM + col;
          if (mat == 0) { Qh[o] = bfu(h); Ql[o] = bfu(l); }
          else          { Kh[o] = bfu(h); Kl[o] = bfu(l); }
        }
      }
  }
}

// ---------------- k_attn helpers ----------------
__device__ __forceinline__ void qk_tile(const u16* kb, int g, int l16,
                                        const bf16x8 qh0[4], const bf16x8 ql0[4],
                                        const bf16x8 qh1[4], const bf16x8 ql1[4],
                                        f32x4& s00, f32x4& s01, f32x4& s10, f32x4& s11) {
  s00 = s01 = s10 = s11 = (f32x4){0.f, 0.f, 0.f, 0.f};
  __builtin_amdgcn_s_setprio(1);
#pragma unroll
  for (int kf = 0; kf < 4; ++kf) {
    int cs = ((kf * 4 + g) ^ l16) << 3;
    bf16x8 kh0 = *(const bf16x8*)(const void*)(kb + l16 * 128 + cs);
    bf16x8 kl0 = *(const bf16x8*)(const void*)(kb + 4096 + l16 * 128 + cs);
    s00 = MFMA(kh0, qh0[kf], s00, 0, 0, 0);
    s00 = MFMA(kh0, ql0[kf], s00, 0, 0, 0);
    s00 = MFMA(kl0, qh0[kf], s00, 0, 0, 0);
    s10 = MFMA(kh0, qh1[kf], s10, 0, 0, 0);
    s10 = MFMA(kh0, ql1[kf], s10, 0, 0, 0);
    s10 = MFMA(kl0, qh1[kf], s10, 0, 0, 0);
    bf16x8 kh1 = *(const bf16x8*)(const void*)(kb + (16 + l16) * 128 + cs);
    bf16x8 kl1 = *(const bf16x8*)(const void*)(kb + 4096 + (16 + l16) * 128 + cs);
    s01 = MFMA(kh1, qh0[kf], s01, 0, 0, 0);
    s01 = MFMA(kh1, ql0[kf], s01, 0, 0, 0);
    s01 = MFMA(kl1, qh0[kf], s01, 0, 0, 0);
    s11 = MFMA(kh1, qh1[kf], s11, 0, 0, 0);
    s11 = MFMA(kh1, ql1[kf], s11, 0, 0, 0);
    s11 = MFMA(kl1, qh1[kf], s11, 0, 0, 0);
  }
  __builtin_amdgcn_s_setprio(0);
}

__device__ __forceinline__ void sm_pack(f32x4 sA, f32x4 sB, float& mr, float& lr,
                                        f32x4 acc[8], int g, bf16x8& pa) {
  float mx = fmaxf(fmaxf(fmaxf(sA[0], sA[1]), fmaxf(sA[2], sA[3])),
                   fmaxf(fmaxf(sB[0], sB[1]), fmaxf(sB[2], sB[3])));
  mx = fmaxf(mx, __shfl_xor(mx, 16, 64));
  mx = fmaxf(mx, __shfl_xor(mx, 32, 64));
  if (!__all(mx - mr <= 8.0f)) {  // defer-rescale (exact math either way)
    float mn = fmaxf(mr, mx);
    float f = __expf(mr - mn);
    lr *= f;
    mr = mn;
    float fr0 = __shfl(f, g * 4 + 0, 64);
    float fr1 = __shfl(f, g * 4 + 1, 64);
    float fr2 = __shfl(f, g * 4 + 2, 64);
    float fr3 = __shfl(f, g * 4 + 3, 64);
#pragma unroll
    for (int nf = 0; nf < 8; ++nf) {
      acc[nf][0] *= fr0; acc[nf][1] *= fr1; acc[nf][2] *= fr2; acc[nf][3] *= fr3;
    }
  }
  float e0 = __expf(sA[0] - mr), e1 = __expf(sA[1] - mr);
  float e2 = __expf(sA[2] - mr), e3 = __expf(sA[3] - mr);
  float e4 = __expf(sB[0] - mr), e5 = __expf(sB[1] - mr);
  float e6 = __expf(sB[2] - mr), e7 = __expf(sB[3] - mr);
  float sm = ((e0 + e1) + (e2 + e3)) + ((e4 + e5) + (e6 + e7));
  sm += __shfl_xor(sm, 16, 64);
  sm += __shfl_xor(sm, 32, 64);
  lr += sm;
  u32 w0 = pk2(e0, e1), w1 = pk2(e2, e3), w2 = pk2(e4, e5), w3 = pk2(e6, e7);
  u32 x0 = __shfl_xor(w0, 16, 64), x1 = __shfl_xor(w1, 16, 64);
  u32 x2 = __shfl_xor(w2, 16, 64), x3 = __shfl_xor(w3, 16, 64);
  bool odd = (g & 1);
  u32x4 pw;
  pw.x = odd ? x2 : w0;
  pw.y = odd ? x3 : w1;
  pw.z = odd ? w2 : x0;
  pw.w = odd ? w3 : x1;
  pa = __builtin_bit_cast(bf16x8, pw);
}

__device__ __forceinline__ void pv_tile(const u16* vb, int mg, int l16,
                                        bf16x8 pa0, bf16x8 pa1,
                                        f32x4 acc0[8], f32x4 acc1[8]) {
  __builtin_amdgcn_s_setprio(1);
#pragma unroll
  for (int nf = 0; nf < 8; ++nf) {
    int d = nf * 16 + l16;
    bf16x8 vf = *(const bf16x8*)(const void*)(vb + d * 32 + ((mg ^ ((d >> 1) & 3)) << 3));
    acc0[nf] = MFMA(pa0, vf, acc0[nf], 0, 0, 0);
    acc1[nf] = MFMA(pa1, vf, acc1[nf], 0, 0, 0);
  }
  __builtin_amdgcn_s_setprio(0);
}

// ---------------- kernel 2: flash attention, software-pipelined QK(i+1) || softmax(i) ----
__global__ __launch_bounds__(512, 2) void k_attn(const u16* __restrict__ Qh, const u16* __restrict__ Ql,
                                                 const u16* __restrict__ Kh, const u16* __restrict__ Kl,
                                                 const u16* __restrict__ VT,
                                                 float* __restrict__ Pm, float* __restrict__ Pl,
                                                 u16* __restrict__ PO) {
  const int bid = blockIdx.x;
  const int sp = bid & 7;     // kv split 0..7 (== XCD id)
  const int qb = bid >> 3;    // 256-row q-block 0..31
  const int b = qb >> 4;
  const int tid = threadIdx.x;
  const int w = tid >> 6, lane = tid & 63, g = lane >> 4, l16 = lane & 15;

  __shared__ alignas(16) u16 kbuf[2][8192];   // [hi 32x128 | lo 32x128] chunk-swizzled
  __shared__ alignas(16) u16 vbuf[3][4096];   // [128d x 32s] chunk-swizzled, triple-buffered

  // ---- Q fragments (hi/lo), 32 q-rows: 2 groups of 16 ----
  const int gr0 = qb * 256 + w * 32;
  bf16x8 qh0[4], ql0[4], qh1[4], ql1[4];
  {
    const u16* p0h = Qh + ((size_t)gr0 + l16) * DIM;
    const u16* p0l = Ql + ((size_t)gr0 + l16) * DIM;
    const u16* p1h = Qh + ((size_t)gr0 + 16 + l16) * DIM;
    const u16* p1l = Ql + ((size_t)gr0 + 16 + l16) * DIM;
#pragma unroll
    for (int kf = 0; kf < 4; ++kf) {
      int d0 = kf * 32 + g * 8;
      qh0[kf] = *(const bf16x8*)(const void*)(p0h + d0);
      ql0[kf] = *(const bf16x8*)(const void*)(p0l + d0);
      qh1[kf] = *(const bf16x8*)(const void*)(p1h + d0);
      ql1[kf] = *(const bf16x8*)(const void*)(p1l + d0);
    }
  }

  f32x4 acc0[8], acc1[8];
#pragma unroll
  for (int nf = 0; nf < 8; ++nf) {
    acc0[nf] = (f32x4){0.f, 0.f, 0.f, 0.f};
    acc1[nf] = (f32x4){0.f, 0.f, 0.f, 0.f};
  }
  float m0 = -1e30f, m1 = -1e30f, l0 = 0.f, l1 = 0.f;

  const int key_base = sp * (S_SRC / NSP);
  const u16* KhB = Kh + (size_t)b * S_SRC * DIM;
  const u16* KlB = Kl + (size_t)b * S_SRC * DIM;
  const u16* VTB = VT + (size_t)b * DIM * S_SRC;

  // staging (512 threads x 3 chunks of 16B), chunk-XOR swizzle
  const int kkey = tid >> 4, kcp = tid & 15;
  const int kcs = (kcp ^ (kkey & 15)) << 3;
  const int vd = tid >> 2, vcp = tid & 3;
  const int vcs = (vcp ^ ((vd >> 1) & 3)) << 3;
  const int wbase = w * 512;
  const int mg = ((g & 1) << 1) | (g >> 1);  // V key-chunk permutation {0,2,1,3}

#define STAGE(KB, VB, KEY0)                                                       \
  {                                                                               \
    g2l16(KhB + ((size_t)((KEY0) + kkey)) * DIM + kcs, &kbuf[KB][wbase]);         \
    g2l16(KlB + ((size_t)((KEY0) + kkey)) * DIM + kcs, &kbuf[KB][4096 + wbase]);  \
    g2l16(VTB + (size_t)vd * S_SRC + (KEY0) + vcs,     &vbuf[VB][wbase]);         \
  }
#define WAITBAR { asm volatile("s_waitcnt vmcnt(0)" ::: "memory"); __builtin_amdgcn_s_barrier(); }

  f32x4 a00, a01, a10, a11;  // scores, set A
  f32x4 b00, b01, b10, b11;  // scores, set B
  bf16x8 pa0, pa1;

  // ---- prologue: stage tiles 0,1; QK(0) ----
  STAGE(0, 0, key_base)
  STAGE(1, 1, key_base + 32)
  asm volatile("s_waitcnt vmcnt(3)" ::: "memory");
  __builtin_amdgcn_s_barrier();
  qk_tile(kbuf[0], g, l16, qh0, ql0, qh1, ql1, a00, a01, a10, a11);
  WAITBAR

  // ---- main loop: 7 unguarded pairs (i = 0..13) ----
  int va = 0;  // vbuf index of tile ii
  for (int ii = 0; ii < NITER - 2; ii += 2) {
    const int v1 = (va + 1) % 3, v2 = (va + 2) % 3;
    // phase A (i = ii): stage K/V[ii+2]; QK(ii+1) -> B; softmax(A); PV(ii)
    STAGE(ii & 1, v2, key_base + (ii + 2) * 32)
    qk_tile(kbuf[(ii & 1) ^ 1], g, l16, qh0, ql0, qh1, ql1, b00, b01, b10, b11);
    sm_pack(a00, a01, m0, l0, acc0, g, pa0);
    sm_pack(a10, a11, m1, l1, acc1, g, pa1);
    pv_tile(vbuf[va], mg, l16, pa0, pa1, acc0, acc1);
    WAITBAR
    // phase B (i = ii+1): stage K/V[ii+3]; QK(ii+2) -> A; softmax(B); PV(ii+1)
    STAGE((ii & 1) ^ 1, va, key_base + (ii + 3) * 32)
    qk_tile(kbuf[ii & 1], g, l16, qh0, ql0, qh1, ql1, a00, a01, a10, a11);
    sm_pack(b00, b01, m0, l0, acc0, g, pa0);
    sm_pack(b10, b11, m1, l1, acc1, g, pa1);
    pv_tile(vbuf[v1], mg, l16, pa0, pa1, acc0, acc1);
    WAITBAR
    va = v2;
  }

  // ---- peeled final pair (i = 14, 15): no staging ----
  {
    const int v1 = (va + 1) % 3;
    qk_tile(kbuf[1], g, l16, qh0, ql0, qh1, ql1, b00, b01, b10, b11);  // QK(15)
    sm_pack(a00, a01, m0, l0, acc0, g, pa0);
    sm_pack(a10, a11, m1, l1, acc1, g, pa1);
    pv_tile(vbuf[va], mg, l16, pa0, pa1, acc0, acc1);                  // PV(14)
    sm_pack(b00, b01, m0, l0, acc0, g, pa0);
    sm_pack(b10, b11, m1, l1, acc1, g, pa1);
    pv_tile(vbuf[v1], mg, l16, pa0, pa1, acc0, acc1);                  // PV(15)
  }

  // ---- write partials (m, l, O) for the 2 16-row groups ----
  const int pidx0 = sp * NQG + (gr0 >> 4);
  {
    u16* po = PO + (size_t)pidx0 * 16 * DIM;
#pragma unroll
    for (int nf = 0; nf < 8; ++nf)
#pragma unroll
      for (int r = 0; r < 4; ++r)
        po[(g * 4 + r) * DIM + nf * 16 + l16] = f2bu(acc0[nf][r]);
    u16* po1 = PO + (size_t)(pidx0 + 1) * 16 * DIM;
#pragma unroll
    for (int nf = 0; nf < 8; ++nf)
#pragma unroll
      for (int r = 0; r < 4; ++r)
        po1[(g * 4 + r) * DIM + nf * 16 + l16] = f2bu(acc1[nf][r]);
  }
  if (g == 0) { Pm[pidx0 * 16 + l16] = m0; Pl[pidx0 * 16 + l16] = l0; }
  if (g == 1) { Pm[(pidx0 + 1) * 16 + l16] = m1; Pl[(pidx0 + 1) * 16 + l16] = l1; }
#undef STAGE
#undef WAITBAR
}

// ---------------- kernel 3: combine KV-split partials (vectorized) ----------------
__global__ __launch_bounds__(64) void k_comb(const float* __restrict__ Pm,
                                             const float* __restrict__ Pl,
                                             const u16* __restrict__ PO,
                                             float* __restrict__ out) {
  const int qg = blockIdx.x;
  const int tid = threadIdx.x;

  __shared__ float sc[NSP][16];  // [split][row]
  if (tid < 16) {
    float m = -1e30f;
#pragma unroll
    for (int s = 0; s < NSP; ++s) m = fmaxf(m, Pm[(s * NQG + qg) * 16 + tid]);
    float den = 0.f;
#pragma unroll
    for (int s = 0; s < NSP; ++s) {
      float e = __expf(Pm[(s * NQG + qg) * 16 + tid] - m);
      sc[s][tid] = e;
      den += Pl[(s * NQG + qg) * 16 + tid] * e;
    }
    float inv = 1.0f / den;
#pragma unroll
    for (int s = 0; s < NSP; ++s) sc[s][tid] *= inv;
  }
  __syncthreads();

  float* op = out + (size_t)qg * 16 * DIM;
  for (int i = tid; i < 16 * DIM / 4; i += 64) {
    int row = (i * 4) >> 7;
    f32x4 a = (f32x4){0.f, 0.f, 0.f, 0.f};
#pragma unroll
    for (int s = 0; s < NSP; ++s) {
      u16x4 p = *(const u16x4*)(const void*)(PO + (size_t)(s * NQG + qg) * 16 * DIM + i * 4);
      float wgt = sc[s][row];
      a[0] += bu2f(p.x) * wgt;
      a[1] += bu2f(p.y) * wgt;
      a[2] += bu2f(p.z) * wgt;
      a[3] += bu2f(p.w) * wgt;
    }
    *(f32x4*)(op + i * 4) = a;
  }
}

extern "C" void kernel_launch(void* const* d_in, const int* in_sizes, int n_in,
                              void* d_out, int out_size, void* d_ws, size_t ws_size,
                              hipStream_t stream) {
  const float* X  = (const float*)d_in[0];
  const float* wq = (const float*)d_in[4];
  const float* wk = (const float*)d_in[5];
  const float* wv = (const float*)d_in[6];
  float* out = (float*)d_out;

  u16* WT = (u16*)d_ws;                       // 3*2*128*128 u16 = 192 KiB
  u16* Qh = WT + 3 * 2 * 128 * 128;
  u16* Ql = Qh + (size_t)BATCH * S_SRC * DIM; // 2 MiB each
  u16* Kh = Ql + (size_t)BATCH * S_SRC * DIM;
  u16* Kl = Kh + (size_t)BATCH * S_SRC * DIM;
  u16* VT = Kl + (size_t)BATCH * S_SRC * DIM; // [B][D][S]
  float* Pm = (float*)(VT + (size_t)BATCH * S_SRC * DIM);  // [NSP*NQG*16] f32
  float* Pl = Pm + (size_t)NSP * NQG * 16;
  u16* PO = (u16*)(Pl + (size_t)NSP * NQG * 16);           // [NSP*NQG*16*128] bf16 = 16 MiB

  hipLaunchKernelGGL(k_wsplit, dim3(192), dim3(256), 0, stream, wq, wk, wv, WT);
  hipLaunchKernelGGL(k_proj, dim3(3 * 256), dim3(256), 0, stream,
                     X, WT, Qh, Ql, Kh, Kl, VT);
  hipLaunchKernelGGL(k_attn, dim3(NQB * NSP), dim3(512), 0, stream,
                     Qh, Ql, Kh, Kl, VT, Pm, Pl, PO);
  hipLaunchKernelGGL(k_comb, dim3(NQG), dim3(64), 0, stream, Pm, Pl, PO, out);
}

// Round 10
// 74.601 us; speedup vs baseline: 1.6791x; 1.0080x over previous
//
#include <hip/hip_runtime.h>
#include <hip/hip_bf16.h>

#define S_SRC 4096
#define DIM 128
#define BATCH 2
#define NSP 8
#define NQB 32    // 256-row q-blocks
#define NQG 512   // 16-row q-groups total
#define NITER 16  // (S_SRC/NSP)/32 key tiles per split

typedef unsigned short u16;
typedef unsigned int u32;
typedef __bf16 bf16x8 __attribute__((ext_vector_type(8)));
typedef float f32x4 __attribute__((ext_vector_type(4)));
typedef u32 u32x4 __attribute__((ext_vector_type(4)));
typedef u16 u16x4 __attribute__((ext_vector_type(4)));

__device__ __forceinline__ __bf16 bf_hi(float x) { return (__bf16)x; }
__device__ __forceinline__ __bf16 bf_lo(float x, __bf16 h) { return (__bf16)(x - (float)h); }
__device__ __forceinline__ u16 bfu(__bf16 h) { return __builtin_bit_cast(u16, h); }
__device__ __forceinline__ u16 f2bu(float x) { return __builtin_bit_cast(u16, (__bf16)x); }
__device__ __forceinline__ float bu2f(u16 u) { return (float)__builtin_bit_cast(__bf16, u); }
__device__ __forceinline__ u32 pk2(float lo, float hi) {
  return (u32)f2bu(lo) | ((u32)f2bu(hi) << 16);
}
__device__ __forceinline__ void g2l16(const u16* src, u16* ldst) {
  __builtin_amdgcn_global_load_lds((const __attribute__((address_space(1))) void*)src,
                                   (__attribute__((address_space(3))) void*)ldst, 16, 0, 0);
}
#define MFMA __builtin_amdgcn_mfma_f32_16x16x32_bf16

// ---------------- kernel 0: transpose + hi/lo split the weight matrices ----------------
__global__ __launch_bounds__(256) void k_wsplit(const float* __restrict__ wq,
                                                const float* __restrict__ wk,
                                                const float* __restrict__ wv,
                                                u16* __restrict__ wt) {
  int idx = blockIdx.x * 256 + threadIdx.x;  // 3*128*128 = 49152
  int mat = idx >> 14;
  int r = idx & 16383;
  int d = r >> 7, e = r & 127;
  const float* w = (mat == 0) ? wq : ((mat == 1) ? wk : wv);
  float x = w[r];
  if (mat == 0) x *= 0.08838834764831845f;  // fold 1/sqrt(128) into Wq
  __bf16 h = bf_hi(x);
  __bf16 l = bf_lo(x, h);
  wt[((mat * 2 + 0) * 128 + e) * 128 + d] = bfu(h);
  wt[((mat * 2 + 1) * 128 + e) * 128 + d] = bfu(l);
}

// ---------------- kernel 1: QKV projection, one matrix per block ----------------
__global__ __launch_bounds__(256) void k_proj(const float* __restrict__ X,
                                              const u16* __restrict__ wt,
                                              u16* __restrict__ Qh, u16* __restrict__ Ql,
                                              u16* __restrict__ Kh, u16* __restrict__ Kl,
                                              u16* __restrict__ VT) {
  const int mat = blockIdx.x >> 8;
  const int t = blockIdx.x & 255;
  const int b = t >> 7;
  const int tile = t & 127;
  const int tid = threadIdx.x;
  const int w = tid >> 6, lane = tid & 63, g = lane >> 4, l16 = lane & 15;

  bf16x8 a_h[2][4], a_l[2][4];
#pragma unroll
  for (int mf = 0; mf < 2; ++mf) {
    int row = tile * 32 + mf * 16 + l16;
    const float* xr = X + ((size_t)b * S_SRC + row) * DIM;
#pragma unroll
    for (int kf = 0; kf < 4; ++kf) {
      int d0 = kf * 32 + g * 8;
      f32x4 x0 = *(const f32x4*)(xr + d0);
      f32x4 x1 = *(const f32x4*)(xr + d0 + 4);
#pragma unroll
      for (int j = 0; j < 4; ++j) {
        __bf16 h0 = bf_hi(x0[j]);
        __bf16 h1 = bf_hi(x1[j]);
        a_h[mf][kf][j] = h0;
        a_l[mf][kf][j] = bf_lo(x0[j], h0);
        a_h[mf][kf][4 + j] = h1;
        a_l[mf][kf][4 + j] = bf_lo(x1[j], h1);
      }
    }
  }

  const u16* wth = wt + (mat * 2 + 0) * 16384;
  const u16* wtl = wt + (mat * 2 + 1) * 16384;
#pragma unroll
  for (int nf = 0; nf < 2; ++nf) {
    int col = w * 32 + nf * 16 + l16;
    f32x4 acc[2];
    acc[0] = (f32x4){0.f, 0.f, 0.f, 0.f};
    acc[1] = (f32x4){0.f, 0.f, 0.f, 0.f};
#pragma unroll
    for (int kf = 0; kf < 4; ++kf) {
      int d0 = kf * 32 + g * 8;
      bf16x8 bh = *(const bf16x8*)(const void*)(wth + col * 128 + d0);
      bf16x8 bl = *(const bf16x8*)(const void*)(wtl + col * 128 + d0);
#pragma unroll
      for (int mf = 0; mf < 2; ++mf) {
        acc[mf] = MFMA(a_h[mf][kf], bh, acc[mf], 0, 0, 0);
        acc[mf] = MFMA(a_h[mf][kf], bl, acc[mf], 0, 0, 0);
        acc[mf] = MFMA(a_l[mf][kf], bh, acc[mf], 0, 0, 0);
      }
    }
#pragma unroll
    for (int mf = 0; mf < 2; ++mf)
#pragma unroll
      for (int r = 0; r < 4; ++r) {
        int row = tile * 32 + mf * 16 + g * 4 + r;
        float v = acc[mf][r];
        if (mat == 2) {
          VT[((size_t)b * DIM + col) * S_SRC + row] = f2bu(v);
        } else {
          __bf16 h = bf_hi(v);
          __bf16 l = bf_lo(v, h);
          size_t o = ((size_t)b * S_SRC + row) * DIM + col;
          if (mat == 0) { Qh[o] = bfu(h); Ql[o] = bfu(l); }
          else          { Kh[o] = bfu(h); Kl[o] = bfu(l); }
        }
      }
  }
}

// ---------------- k_attn helpers ----------------
__device__ __forceinline__ void qk_tile(const u16* kb, int g, int l16,
                                        const bf16x8 qh0[4], const bf16x8 ql0[4],
                                        const bf16x8 qh1[4], const bf16x8 ql1[4],
                                        f32x4& s00, f32x4& s01, f32x4& s10, f32x4& s11) {
  s00 = s01 = s10 = s11 = (f32x4){0.f, 0.f, 0.f, 0.f};
  __builtin_amdgcn_s_setprio(1);
#pragma unroll
  for (int kf = 0; kf < 4; ++kf) {
    int cs = ((kf * 4 + g) ^ l16) << 3;
    bf16x8 kh0 = *(const bf16x8*)(const void*)(kb + l16 * 128 + cs);
    bf16x8 kl0 = *(const bf16x8*)(const void*)(kb + 4096 + l16 * 128 + cs);
    s00 = MFMA(kh0, qh0[kf], s00, 0, 0, 0);
    s00 = MFMA(kh0, ql0[kf], s00, 0, 0, 0);
    s00 = MFMA(kl0, qh0[kf], s00, 0, 0, 0);
    s10 = MFMA(kh0, qh1[kf], s10, 0, 0, 0);
    s10 = MFMA(kh0, ql1[kf], s10, 0, 0, 0);
    s10 = MFMA(kl0, qh1[kf], s10, 0, 0, 0);
    bf16x8 kh1 = *(const bf16x8*)(const void*)(kb + (16 + l16) * 128 + cs);
    bf16x8 kl1 = *(const bf16x8*)(const void*)(kb + 4096 + (16 + l16) * 128 + cs);
    s01 = MFMA(kh1, qh0[kf], s01, 0, 0, 0);
    s01 = MFMA(kh1, ql0[kf], s01, 0, 0, 0);
    s01 = MFMA(kl1, qh0[kf], s01, 0, 0, 0);
    s11 = MFMA(kh1, qh1[kf], s11, 0, 0, 0);
    s11 = MFMA(kh1, ql1[kf], s11, 0, 0, 0);
    s11 = MFMA(kl1, qh1[kf], s11, 0, 0, 0);
  }
  __builtin_amdgcn_s_setprio(0);
}

__device__ __forceinline__ void sm_pack(f32x4 sA, f32x4 sB, float& mr, float& lr,
                                        f32x4 acc[8], int g, bf16x8& pa) {
  float mx = fmaxf(fmaxf(fmaxf(sA[0], sA[1]), fmaxf(sA[2], sA[3])),
                   fmaxf(fmaxf(sB[0], sB[1]), fmaxf(sB[2], sB[3])));
  mx = fmaxf(mx, __shfl_xor(mx, 16, 64));
  mx = fmaxf(mx, __shfl_xor(mx, 32, 64));
  if (!__all(mx - mr <= 8.0f)) {  // defer-rescale (exact math either way)
    float mn = fmaxf(mr, mx);
    float f = __expf(mr - mn);
    lr *= f;
    mr = mn;
    float fr0 = __shfl(f, g * 4 + 0, 64);
    float fr1 = __shfl(f, g * 4 + 1, 64);
    float fr2 = __shfl(f, g * 4 + 2, 64);
    float fr3 = __shfl(f, g * 4 + 3, 64);
#pragma unroll
    for (int nf = 0; nf < 8; ++nf) {
      acc[nf][0] *= fr0; acc[nf][1] *= fr1; acc[nf][2] *= fr2; acc[nf][3] *= fr3;
    }
  }
  float e0 = __expf(sA[0] - mr), e1 = __expf(sA[1] - mr);
  float e2 = __expf(sA[2] - mr), e3 = __expf(sA[3] - mr);
  float e4 = __expf(sB[0] - mr), e5 = __expf(sB[1] - mr);
  float e6 = __expf(sB[2] - mr), e7 = __expf(sB[3] - mr);
  float sm = ((e0 + e1) + (e2 + e3)) + ((e4 + e5) + (e6 + e7));
  sm += __shfl_xor(sm, 16, 64);
  sm += __shfl_xor(sm, 32, 64);
  lr += sm;
  u32 w0 = pk2(e0, e1), w1 = pk2(e2, e3), w2 = pk2(e4, e5), w3 = pk2(e6, e7);
  u32 x0 = __shfl_xor(w0, 16, 64), x1 = __shfl_xor(w1, 16, 64);
  u32 x2 = __shfl_xor(w2, 16, 64), x3 = __shfl_xor(w3, 16, 64);
  bool odd = (g & 1);
  u32x4 pw;
  pw.x = odd ? x2 : w0;
  pw.y = odd ? x3 : w1;
  pw.z = odd ? w2 : x0;
  pw.w = odd ? w3 : x1;
  pa = __builtin_bit_cast(bf16x8, pw);
}

__device__ __forceinline__ void pv_tile(const u16* vb, int mg, int l16,
                                        bf16x8 pa0, bf16x8 pa1,
                                        f32x4 acc0[8], f32x4 acc1[8]) {
  __builtin_amdgcn_s_setprio(1);
#pragma unroll
  for (int nf = 0; nf < 8; ++nf) {
    int d = nf * 16 + l16;
    bf16x8 vf = *(const bf16x8*)(const void*)(vb + d * 32 + ((mg ^ ((d >> 1) & 3)) << 3));
    acc0[nf] = MFMA(pa0, vf, acc0[nf], 0, 0, 0);
    acc1[nf] = MFMA(pa1, vf, acc1[nf], 0, 0, 0);
  }
  __builtin_amdgcn_s_setprio(0);
}

// ---------------- kernel 2: flash attention, depth-2 prefetch, counted vmcnt ----------------
// 4-deep K/V ring: window i consumes tile staged 2 windows ago; STAGE(i+2) issued at top.
// vmcnt(6) = 2 STAGEs (3 loads each) stay in flight across the single per-window barrier.
__global__ __launch_bounds__(512, 2) void k_attn(const u16* __restrict__ Qh, const u16* __restrict__ Ql,
                                                 const u16* __restrict__ Kh, const u16* __restrict__ Kl,
                                                 const u16* __restrict__ VT,
                                                 float* __restrict__ Pm, float* __restrict__ Pl,
                                                 u16* __restrict__ PO) {
  const int bid = blockIdx.x;
  const int sp = bid & 7;     // kv split 0..7 (== XCD id)
  const int qb = bid >> 3;    // 256-row q-block 0..31
  const int b = qb >> 4;
  const int tid = threadIdx.x;
  const int w = tid >> 6, lane = tid & 63, g = lane >> 4, l16 = lane & 15;

  __shared__ alignas(16) u16 kbuf[4][8192];   // 64KB: [hi 32x128 | lo 32x128] chunk-swizzled
  __shared__ alignas(16) u16 vbuf[4][4096];   // 32KB: [128d x 32s] chunk-swizzled

  // ---- Q fragments (hi/lo), 32 q-rows: 2 groups of 16 ----
  const int gr0 = qb * 256 + w * 32;
  bf16x8 qh0[4], ql0[4], qh1[4], ql1[4];
  {
    const u16* p0h = Qh + ((size_t)gr0 + l16) * DIM;
    const u16* p0l = Ql + ((size_t)gr0 + l16) * DIM;
    const u16* p1h = Qh + ((size_t)gr0 + 16 + l16) * DIM;
    const u16* p1l = Ql + ((size_t)gr0 + 16 + l16) * DIM;
#pragma unroll
    for (int kf = 0; kf < 4; ++kf) {
      int d0 = kf * 32 + g * 8;
      qh0[kf] = *(const bf16x8*)(const void*)(p0h + d0);
      ql0[kf] = *(const bf16x8*)(const void*)(p0l + d0);
      qh1[kf] = *(const bf16x8*)(const void*)(p1h + d0);
      ql1[kf] = *(const bf16x8*)(const void*)(p1l + d0);
    }
  }

  f32x4 acc0[8], acc1[8];
#pragma unroll
  for (int nf = 0; nf < 8; ++nf) {
    acc0[nf] = (f32x4){0.f, 0.f, 0.f, 0.f};
    acc1[nf] = (f32x4){0.f, 0.f, 0.f, 0.f};
  }
  float m0 = -1e30f, m1 = -1e30f, l0 = 0.f, l1 = 0.f;

  const int key_base = sp * (S_SRC / NSP);
  const u16* KhB = Kh + (size_t)b * S_SRC * DIM;
  const u16* KlB = Kl + (size_t)b * S_SRC * DIM;
  const u16* VTB = VT + (size_t)b * DIM * S_SRC;

  // staging (512 threads x 3 chunks of 16B), chunk-XOR swizzle
  const int kkey = tid >> 4, kcp = tid & 15;
  const int kcs = (kcp ^ (kkey & 15)) << 3;
  const int vd = tid >> 2, vcp = tid & 3;
  const int vcs = (vcp ^ ((vd >> 1) & 3)) << 3;
  const int wbase = w * 512;
  const int mg = ((g & 1) << 1) | (g >> 1);  // V key-chunk permutation {0,2,1,3}

#define STAGE(BUF, KEY0)                                                        \
  {                                                                             \
    g2l16(KhB + ((size_t)((KEY0) + kkey)) * DIM + kcs, &kbuf[BUF][wbase]);      \
    g2l16(KlB + ((size_t)((KEY0) + kkey)) * DIM + kcs, &kbuf[BUF][4096 + wbase]); \
    g2l16(VTB + (size_t)vd * S_SRC + (KEY0) + vcs,     &vbuf[BUF][wbase]);      \
  }
#define BODY(I)                                                                  \
  {                                                                              \
    f32x4 s00, s01, s10, s11;                                                    \
    qk_tile(kbuf[(I) & 3], g, l16, qh0, ql0, qh1, ql1, s00, s01, s10, s11);      \
    bf16x8 pa0, pa1;                                                             \
    sm_pack(s00, s01, m0, l0, acc0, g, pa0);                                     \
    sm_pack(s10, s11, m1, l1, acc1, g, pa1);                                     \
    pv_tile(vbuf[(I) & 3], mg, l16, pa0, pa1, acc0, acc1);                       \
  }

  // ---- prologue: stage tiles 0,1 (6 loads in flight) ----
  STAGE(0, key_base)
  STAGE(1, key_base + 32)

  // ---- main loop: depth-2 pipeline, single barrier per window ----
  for (int i = 0; i < NITER - 2; ++i) {
    STAGE((i + 2) & 3, key_base + (i + 2) * 32)
    asm volatile("s_waitcnt vmcnt(6)" ::: "memory");  // tile i landed; i+1, i+2 in flight
    __builtin_amdgcn_s_barrier();
    BODY(i)
  }
  // ---- tail: i = NITER-2, NITER-1 ----
  asm volatile("s_waitcnt vmcnt(3)" ::: "memory");
  __builtin_amdgcn_s_barrier();
  BODY(NITER - 2)
  asm volatile("s_waitcnt vmcnt(0)" ::: "memory");
  __builtin_amdgcn_s_barrier();
  BODY(NITER - 1)

  // ---- write partials (m, l, O) for the 2 16-row groups ----
  const int pidx0 = sp * NQG + (gr0 >> 4);
  {
    u16* po = PO + (size_t)pidx0 * 16 * DIM;
#pragma unroll
    for (int nf = 0; nf < 8; ++nf)
#pragma unroll
      for (int r = 0; r < 4; ++r)
        po[(g * 4 + r) * DIM + nf * 16 + l16] = f2bu(acc0[nf][r]);
    u16* po1 = PO + (size_t)(pidx0 + 1) * 16 * DIM;
#pragma unroll
    for (int nf = 0; nf < 8; ++nf)
#pragma unroll
      for (int r = 0; r < 4; ++r)
        po1[(g * 4 + r) * DIM + nf * 16 + l16] = f2bu(acc1[nf][r]);
  }
  if (g == 0) { Pm[pidx0 * 16 + l16] = m0; Pl[pidx0 * 16 + l16] = l0; }
  if (g == 1) { Pm[(pidx0 + 1) * 16 + l16] = m1; Pl[(pidx0 + 1) * 16 + l16] = l1; }
#undef STAGE
#undef BODY
}

// ---------------- kernel 3: combine KV-split partials (vectorized) ----------------
__global__ __launch_bounds__(64) void k_comb(const float* __restrict__ Pm,
                                             const float* __restrict__ Pl,
                                             const u16* __restrict__ PO,
                                             float* __restrict__ out) {
  const int qg = blockIdx.x;
  const int tid = threadIdx.x;

  __shared__ float sc[NSP][16];  // [split][row]
  if (tid < 16) {
    float m = -1e30f;
#pragma unroll
    for (int s = 0; s < NSP; ++s) m = fmaxf(m, Pm[(s * NQG + qg) * 16 + tid]);
    float den = 0.f;
#pragma unroll
    for (int s = 0; s < NSP; ++s) {
      float e = __expf(Pm[(s * NQG + qg) * 16 + tid] - m);
      sc[s][tid] = e;
      den += Pl[(s * NQG + qg) * 16 + tid] * e;
    }
    float inv = 1.0f / den;
#pragma unroll
    for (int s = 0; s < NSP; ++s) sc[s][tid] *= inv;
  }
  __syncthreads();

  float* op = out + (size_t)qg * 16 * DIM;
  for (int i = tid; i < 16 * DIM / 4; i += 64) {
    int row = (i * 4) >> 7;
    f32x4 a = (f32x4){0.f, 0.f, 0.f, 0.f};
#pragma unroll
    for (int s = 0; s < NSP; ++s) {
      u16x4 p = *(const u16x4*)(const void*)(PO + (size_t)(s * NQG + qg) * 16 * DIM + i * 4);
      float wgt = sc[s][row];
      a[0] += bu2f(p.x) * wgt;
      a[1] += bu2f(p.y) * wgt;
      a[2] += bu2f(p.z) * wgt;
      a[3] += bu2f(p.w) * wgt;
    }
    *(f32x4*)(op + i * 4) = a;
  }
}

extern "C" void kernel_launch(void* const* d_in, const int* in_sizes, int n_in,
                              void* d_out, int out_size, void* d_ws, size_t ws_size,
                              hipStream_t stream) {
  const float* X  = (const float*)d_in[0];
  const float* wq = (const float*)d_in[4];
  const float* wk = (const float*)d_in[5];
  const float* wv = (const float*)d_in[6];
  float* out = (float*)d_out;

  u16* WT = (u16*)d_ws;                       // 3*2*128*128 u16 = 192 KiB
  u16* Qh = WT + 3 * 2 * 128 * 128;
  u16* Ql = Qh + (size_t)BATCH * S_SRC * DIM; // 2 MiB each
  u16* Kh = Ql + (size_t)BATCH * S_SRC * DIM;
  u16* Kl = Kh + (size_t)BATCH * S_SRC * DIM;
  u16* VT = Kl + (size_t)BATCH * S_SRC * DIM; // [B][D][S]
  float* Pm = (float*)(VT + (size_t)BATCH * S_SRC * DIM);  // [NSP*NQG*16] f32
  float* Pl = Pm + (size_t)NSP * NQG * 16;
  u16* PO = (u16*)(Pl + (size_t)NSP * NQG * 16);           // [NSP*NQG*16*128] bf16 = 16 MiB

  hipLaunchKernelGGL(k_wsplit, dim3(192), dim3(256), 0, stream, wq, wk, wv, WT);
  hipLaunchKernelGGL(k_proj, dim3(3 * 256), dim3(256), 0, stream,
                     X, WT, Qh, Ql, Kh, Kl, VT);
  hipLaunchKernelGGL(k_attn, dim3(NQB * NSP), dim3(512), 0, stream,
                     Qh, Ql, Kh, Kl, VT, Pm, Pl, PO);
  hipLaunchKernelGGL(k_comb, dim3(NQG), dim3(64), 0, stream, Pm, Pl, PO, out);
}

// Round 11
// 72.536 us; speedup vs baseline: 1.7269x; 1.0285x over previous
//
#include <hip/hip_runtime.h>
#include <hip/hip_bf16.h>

#define S_SRC 4096
#define DIM 128
#define BATCH 2
#define NSP 8
#define NQB 32    // 256-row q-blocks
#define NQG 512   // 16-row q-groups total
#define NWIN 8    // (S_SRC/NSP)/64 key windows per split

typedef unsigned short u16;
typedef unsigned int u32;
typedef __bf16 bf16x8 __attribute__((ext_vector_type(8)));
typedef float f32x4 __attribute__((ext_vector_type(4)));
typedef u32 u32x4 __attribute__((ext_vector_type(4)));
typedef u16 u16x4 __attribute__((ext_vector_type(4)));

__device__ __forceinline__ __bf16 bf_hi(float x) { return (__bf16)x; }
__device__ __forceinline__ __bf16 bf_lo(float x, __bf16 h) { return (__bf16)(x - (float)h); }
__device__ __forceinline__ u16 bfu(__bf16 h) { return __builtin_bit_cast(u16, h); }
__device__ __forceinline__ u16 f2bu(float x) { return __builtin_bit_cast(u16, (__bf16)x); }
__device__ __forceinline__ float bu2f(u16 u) { return (float)__builtin_bit_cast(__bf16, u); }
__device__ __forceinline__ u32 pk2(float lo, float hi) {
  return (u32)f2bu(lo) | ((u32)f2bu(hi) << 16);
}
__device__ __forceinline__ void g2l16(const u16* src, u16* ldst) {
  __builtin_amdgcn_global_load_lds((const __attribute__((address_space(1))) void*)src,
                                   (__attribute__((address_space(3))) void*)ldst, 16, 0, 0);
}
#define MFMA __builtin_amdgcn_mfma_f32_16x16x32_bf16

// ---------------- kernel 0: transpose + hi/lo split the weight matrices ----------------
__global__ __launch_bounds__(256) void k_wsplit(const float* __restrict__ wq,
                                                const float* __restrict__ wk,
                                                const float* __restrict__ wv,
                                                u16* __restrict__ wt) {
  int idx = blockIdx.x * 256 + threadIdx.x;  // 3*128*128 = 49152
  int mat = idx >> 14;
  int r = idx & 16383;
  int d = r >> 7, e = r & 127;
  const float* w = (mat == 0) ? wq : ((mat == 1) ? wk : wv);
  float x = w[r];
  if (mat == 0) x *= 0.08838834764831845f;  // fold 1/sqrt(128) into Wq
  __bf16 h = bf_hi(x);
  __bf16 l = bf_lo(x, h);
  wt[((mat * 2 + 0) * 128 + e) * 128 + d] = bfu(h);
  wt[((mat * 2 + 1) * 128 + e) * 128 + d] = bfu(l);
}

// ---------------- kernel 1: QKV projection, one matrix per block ----------------
__global__ __launch_bounds__(256) void k_proj(const float* __restrict__ X,
                                              const u16* __restrict__ wt,
                                              u16* __restrict__ Qh, u16* __restrict__ Ql,
                                              u16* __restrict__ Kh, u16* __restrict__ Kl,
                                              u16* __restrict__ VT) {
  const int mat = blockIdx.x >> 8;
  const int t = blockIdx.x & 255;
  const int b = t >> 7;
  const int tile = t & 127;
  const int tid = threadIdx.x;
  const int w = tid >> 6, lane = tid & 63, g = lane >> 4, l16 = lane & 15;

  bf16x8 a_h[2][4], a_l[2][4];
#pragma unroll
  for (int mf = 0; mf < 2; ++mf) {
    int row = tile * 32 + mf * 16 + l16;
    const float* xr = X + ((size_t)b * S_SRC + row) * DIM;
#pragma unroll
    for (int kf = 0; kf < 4; ++kf) {
      int d0 = kf * 32 + g * 8;
      f32x4 x0 = *(const f32x4*)(xr + d0);
      f32x4 x1 = *(const f32x4*)(xr + d0 + 4);
#pragma unroll
      for (int j = 0; j < 4; ++j) {
        __bf16 h0 = bf_hi(x0[j]);
        __bf16 h1 = bf_hi(x1[j]);
        a_h[mf][kf][j] = h0;
        a_l[mf][kf][j] = bf_lo(x0[j], h0);
        a_h[mf][kf][4 + j] = h1;
        a_l[mf][kf][4 + j] = bf_lo(x1[j], h1);
      }
    }
  }

  const u16* wth = wt + (mat * 2 + 0) * 16384;
  const u16* wtl = wt + (mat * 2 + 1) * 16384;
#pragma unroll
  for (int nf = 0; nf < 2; ++nf) {
    int col = w * 32 + nf * 16 + l16;
    f32x4 acc[2];
    acc[0] = (f32x4){0.f, 0.f, 0.f, 0.f};
    acc[1] = (f32x4){0.f, 0.f, 0.f, 0.f};
#pragma unroll
    for (int kf = 0; kf < 4; ++kf) {
      int d0 = kf * 32 + g * 8;
      bf16x8 bh = *(const bf16x8*)(const void*)(wth + col * 128 + d0);
      bf16x8 bl = *(const bf16x8*)(const void*)(wtl + col * 128 + d0);
#pragma unroll
      for (int mf = 0; mf < 2; ++mf) {
        acc[mf] = MFMA(a_h[mf][kf], bh, acc[mf], 0, 0, 0);
        acc[mf] = MFMA(a_h[mf][kf], bl, acc[mf], 0, 0, 0);
        acc[mf] = MFMA(a_l[mf][kf], bh, acc[mf], 0, 0, 0);
      }
    }
#pragma unroll
    for (int mf = 0; mf < 2; ++mf)
#pragma unroll
      for (int r = 0; r < 4; ++r) {
        int row = tile * 32 + mf * 16 + g * 4 + r;
        float v = acc[mf][r];
        if (mat == 2) {
          VT[((size_t)b * DIM + col) * S_SRC + row] = f2bu(v);
        } else {
          __bf16 h = bf_hi(v);
          __bf16 l = bf_lo(v, h);
          size_t o = ((size_t)b * S_SRC + row) * DIM + col;
          if (mat == 0) { Qh[o] = bfu(h); Ql[o] = bfu(l); }
          else          { Kh[o] = bfu(h); Kl[o] = bfu(l); }
        }
      }
  }
}

// ---------------- kernel 2: flash attention, 64-key windows, 3-deep ring ----------------
// Swapped QK^T (A=K, B=Q). Per wave: 2 q-groups of 16 rows. 8 windows of 64 keys.
__global__ __launch_bounds__(512, 2) void k_attn(const u16* __restrict__ Qh, const u16* __restrict__ Ql,
                                                 const u16* __restrict__ Kh, const u16* __restrict__ Kl,
                                                 const u16* __restrict__ VT,
                                                 float* __restrict__ Pm, float* __restrict__ Pl,
                                                 u16* __restrict__ PO) {
  const int bid = blockIdx.x;
  const int sp = bid & 7;     // kv split 0..7 (== XCD id)
  const int qb = bid >> 3;    // 256-row q-block 0..31
  const int b = qb >> 4;
  const int tid = threadIdx.x;
  const int w = tid >> 6, lane = tid & 63, g = lane >> 4, l16 = lane & 15;

  __shared__ alignas(16) u16 kbuf[3][16384];  // 96KB: [hi 64x128 | lo 64x128] chunk-swizzled
  __shared__ alignas(16) u16 vbuf[3][8192];   // 48KB: [128d x 64s] chunk-swizzled

  // ---- Q fragments (hi/lo), 32 q-rows: 2 groups of 16 ----
  const int gr0 = qb * 256 + w * 32;
  bf16x8 qh0[4], ql0[4], qh1[4], ql1[4];
  {
    const u16* p0h = Qh + ((size_t)gr0 + l16) * DIM;
    const u16* p0l = Ql + ((size_t)gr0 + l16) * DIM;
    const u16* p1h = Qh + ((size_t)gr0 + 16 + l16) * DIM;
    const u16* p1l = Ql + ((size_t)gr0 + 16 + l16) * DIM;
#pragma unroll
    for (int kf = 0; kf < 4; ++kf) {
      int d0 = kf * 32 + g * 8;
      qh0[kf] = *(const bf16x8*)(const void*)(p0h + d0);
      ql0[kf] = *(const bf16x8*)(const void*)(p0l + d0);
      qh1[kf] = *(const bf16x8*)(const void*)(p1h + d0);
      ql1[kf] = *(const bf16x8*)(const void*)(p1l + d0);
    }
  }

  f32x4 acc0[8], acc1[8];
#pragma unroll
  for (int nf = 0; nf < 8; ++nf) {
    acc0[nf] = (f32x4){0.f, 0.f, 0.f, 0.f};
    acc1[nf] = (f32x4){0.f, 0.f, 0.f, 0.f};
  }
  float m0 = -1e30f, m1 = -1e30f, l0 = 0.f, l1 = 0.f;

  const int key_base = sp * (S_SRC / NSP);
  const u16* KhB = Kh + (size_t)b * S_SRC * DIM;
  const u16* KlB = Kl + (size_t)b * S_SRC * DIM;
  const u16* VTB = VT + (size_t)b * DIM * S_SRC;

  // staging (512 threads x 6 chunks of 16B), chunk-XOR swizzle
  const int kkey0 = tid >> 4;                           // key row 0..31 (pass0); +32 pass1
  const int kks = ((tid & 15) ^ (kkey0 & 15)) << 3;     // swizzled source d-offset (elems)
  const int vd0 = tid >> 3;                             // V d-row 0..63 (pass0); +64 pass1
  const int vks = ((tid & 7) ^ ((vd0 >> 1) & 7)) << 3;  // swizzled source s-offset (elems)
  const int wb = w * 512;                               // wave-uniform LDS chunk base (u16)
  const int mg = ((g & 1) << 1) | (g >> 1);             // V key-chunk permutation {0,2,1,3}

#define STAGE(BUF, KEY0)                                                             \
  {                                                                                  \
    g2l16(KhB + ((size_t)((KEY0) + kkey0)) * DIM + kks,      &kbuf[BUF][wb]);        \
    g2l16(KhB + ((size_t)((KEY0) + 32 + kkey0)) * DIM + kks, &kbuf[BUF][4096 + wb]); \
    g2l16(KlB + ((size_t)((KEY0) + kkey0)) * DIM + kks,      &kbuf[BUF][8192 + wb]); \
    g2l16(KlB + ((size_t)((KEY0) + 32 + kkey0)) * DIM + kks, &kbuf[BUF][12288 + wb]);\
    g2l16(VTB + (size_t)vd0 * S_SRC + (KEY0) + vks,          &vbuf[BUF][wb]);        \
    g2l16(VTB + (size_t)(64 + vd0) * S_SRC + (KEY0) + vks,   &vbuf[BUF][4096 + wb]); \
  }

// S = f32x4[4] score array (keys st*16 + g*4 + r of q-col l16), MR/LR running stats,
// ACC = f32x4[8] output acc, PA/PB = packed P A-frags for key-chunks 0/1.
#define SMPACK(S, MR, LR, ACC, PA, PB)                                               \
  {                                                                                  \
    float mxa = fmaxf(fmaxf(fmaxf(S[0][0], S[0][1]), fmaxf(S[0][2], S[0][3])),       \
                      fmaxf(fmaxf(S[1][0], S[1][1]), fmaxf(S[1][2], S[1][3])));      \
    float mxb = fmaxf(fmaxf(fmaxf(S[2][0], S[2][1]), fmaxf(S[2][2], S[2][3])),       \
                      fmaxf(fmaxf(S[3][0], S[3][1]), fmaxf(S[3][2], S[3][3])));      \
    float mx = fmaxf(mxa, mxb);                                                      \
    mx = fmaxf(mx, __shfl_xor(mx, 16, 64));                                          \
    mx = fmaxf(mx, __shfl_xor(mx, 32, 64));                                          \
    if (!__all(mx - MR <= 8.0f)) {                                                   \
      float mn = fmaxf(MR, mx);                                                      \
      float f = __expf(MR - mn);                                                     \
      LR *= f; MR = mn;                                                              \
      float fr0 = __shfl(f, g * 4 + 0, 64);                                          \
      float fr1 = __shfl(f, g * 4 + 1, 64);                                          \
      float fr2 = __shfl(f, g * 4 + 2, 64);                                          \
      float fr3 = __shfl(f, g * 4 + 3, 64);                                          \
      _Pragma("unroll")                                                              \
      for (int nf = 0; nf < 8; ++nf) {                                               \
        ACC[nf][0] *= fr0; ACC[nf][1] *= fr1;                                        \
        ACC[nf][2] *= fr2; ACC[nf][3] *= fr3;                                        \
      }                                                                              \
    }                                                                                \
    float e0 = __expf(S[0][0] - MR), e1 = __expf(S[0][1] - MR);                      \
    float e2 = __expf(S[0][2] - MR), e3 = __expf(S[0][3] - MR);                      \
    float e4 = __expf(S[1][0] - MR), e5 = __expf(S[1][1] - MR);                      \
    float e6 = __expf(S[1][2] - MR), e7 = __expf(S[1][3] - MR);                      \
    float f0 = __expf(S[2][0] - MR), f1 = __expf(S[2][1] - MR);                      \
    float f2 = __expf(S[2][2] - MR), f3 = __expf(S[2][3] - MR);                      \
    float f4 = __expf(S[3][0] - MR), f5 = __expf(S[3][1] - MR);                      \
    float f6 = __expf(S[3][2] - MR), f7 = __expf(S[3][3] - MR);                      \
    float sm = (((e0 + e1) + (e2 + e3)) + ((e4 + e5) + (e6 + e7)))                   \
             + (((f0 + f1) + (f2 + f3)) + ((f4 + f5) + (f6 + f7)));                  \
    sm += __shfl_xor(sm, 16, 64);                                                    \
    sm += __shfl_xor(sm, 32, 64);                                                    \
    LR += sm;                                                                        \
    bool odd = (g & 1);                                                              \
    {                                                                                \
      u32 w0 = pk2(e0, e1), w1 = pk2(e2, e3), w2 = pk2(e4, e5), w3 = pk2(e6, e7);    \
      u32 x0 = __shfl_xor(w0, 16, 64), x1 = __shfl_xor(w1, 16, 64);                  \
      u32 x2 = __shfl_xor(w2, 16, 64), x3 = __shfl_xor(w3, 16, 64);                  \
      u32x4 pw;                                                                      \
      pw.x = odd ? x2 : w0; pw.y = odd ? x3 : w1;                                    \
      pw.z = odd ? w2 : x0; pw.w = odd ? w3 : x1;                                    \
      PA = __builtin_bit_cast(bf16x8, pw);                                           \
    }                                                                                \
    {                                                                                \
      u32 w0 = pk2(f0, f1), w1 = pk2(f2, f3), w2 = pk2(f4, f5), w3 = pk2(f6, f7);    \
      u32 x0 = __shfl_xor(w0, 16, 64), x1 = __shfl_xor(w1, 16, 64);                  \
      u32 x2 = __shfl_xor(w2, 16, 64), x3 = __shfl_xor(w3, 16, 64);                  \
      u32x4 pw;                                                                      \
      pw.x = odd ? x2 : w0; pw.y = odd ? x3 : w1;                                    \
      pw.z = odd ? w2 : x0; pw.w = odd ? w3 : x1;                                    \
      PB = __builtin_bit_cast(bf16x8, pw);                                           \
    }                                                                                \
  }

  // ---- prologue: stage tiles 0,1 (12 loads in flight) ----
  STAGE(0, key_base)
  STAGE(1, key_base + 64)

  int cur = 0;  // ring buffer holding tile i
  for (int i = 0; i < NWIN; ++i) {
    if (i < NWIN - 1) {
      asm volatile("s_waitcnt vmcnt(6)" ::: "memory");  // tile i landed; tile i+1 in flight
    } else {
      asm volatile("s_waitcnt vmcnt(0)" ::: "memory");
    }
    __builtin_amdgcn_s_barrier();  // all waves' tile-i DMAs + prior-window reads done
    if (i + 2 < NWIN) {
      int nx = cur + 2; nx = (nx >= 3) ? nx - 3 : nx;
      STAGE(nx, key_base + (i + 2) * 64)
    }

    const u16* kb = kbuf[cur];
    const u16* vb = vbuf[cur];

    // ---- QK^T swapped, 64 keys x 32 q-rows: each K-frag read feeds both q-groups ----
    f32x4 sg0[4], sg1[4];
#pragma unroll
    for (int st = 0; st < 4; ++st) {
      sg0[st] = (f32x4){0.f, 0.f, 0.f, 0.f};
      sg1[st] = (f32x4){0.f, 0.f, 0.f, 0.f};
    }
    __builtin_amdgcn_s_setprio(1);
#pragma unroll
    for (int kf = 0; kf < 4; ++kf) {
      int cs = ((kf * 4 + g) ^ l16) << 3;
#pragma unroll
      for (int st = 0; st < 4; ++st) {
        const u16* kp = kb + (st * 16 + l16) * 128 + cs;
        bf16x8 kh = *(const bf16x8*)(const void*)kp;
        bf16x8 kl = *(const bf16x8*)(const void*)(kp + 8192);
        sg0[st] = MFMA(kh, qh0[kf], sg0[st], 0, 0, 0);
        sg0[st] = MFMA(kh, ql0[kf], sg0[st], 0, 0, 0);
        sg0[st] = MFMA(kl, qh0[kf], sg0[st], 0, 0, 0);
        sg1[st] = MFMA(kh, qh1[kf], sg1[st], 0, 0, 0);
        sg1[st] = MFMA(kh, ql1[kf], sg1[st], 0, 0, 0);
        sg1[st] = MFMA(kl, qh1[kf], sg1[st], 0, 0, 0);
      }
    }
    __builtin_amdgcn_s_setprio(0);

    // ---- softmax + P-pack, one chain per group per 64 keys ----
    bf16x8 pa0A, pa0B, pa1A, pa1B;
    SMPACK(sg0, m0, l0, acc0, pa0A, pa0B)
    SMPACK(sg1, m1, l1, acc1, pa1A, pa1B)

    // ---- PV: one V-frag pair feeds both q-groups ----
    __builtin_amdgcn_s_setprio(1);
#pragma unroll
    for (int nf = 0; nf < 8; ++nf) {
      int d = nf * 16 + l16;
      int sw = (d >> 1) & 7;
      const u16* vr = vb + d * 64;
      bf16x8 vf0 = *(const bf16x8*)(const void*)(vr + ((mg ^ sw) << 3));
      bf16x8 vf1 = *(const bf16x8*)(const void*)(vr + (((4 + mg) ^ sw) << 3));
      acc0[nf] = MFMA(pa0A, vf0, acc0[nf], 0, 0, 0);
      acc0[nf] = MFMA(pa0B, vf1, acc0[nf], 0, 0, 0);
      acc1[nf] = MFMA(pa1A, vf0, acc1[nf], 0, 0, 0);
      acc1[nf] = MFMA(pa1B, vf1, acc1[nf], 0, 0, 0);
    }
    __builtin_amdgcn_s_setprio(0);

    cur = (cur + 1 >= 3) ? cur - 2 : cur + 1;
  }

  // ---- write partials (m, l, O) for the 2 16-row groups ----
  const int pidx0 = sp * NQG + (gr0 >> 4);
  {
    u16* po = PO + (size_t)pidx0 * 16 * DIM;
#pragma unroll
    for (int nf = 0; nf < 8; ++nf)
#pragma unroll
      for (int r = 0; r < 4; ++r)
        po[(g * 4 + r) * DIM + nf * 16 + l16] = f2bu(acc0[nf][r]);
    u16* po1 = PO + (size_t)(pidx0 + 1) * 16 * DIM;
#pragma unroll
    for (int nf = 0; nf < 8; ++nf)
#pragma unroll
      for (int r = 0; r < 4; ++r)
        po1[(g * 4 + r) * DIM + nf * 16 + l16] = f2bu(acc1[nf][r]);
  }
  if (g == 0) { Pm[pidx0 * 16 + l16] = m0; Pl[pidx0 * 16 + l16] = l0; }
  if (g == 1) { Pm[(pidx0 + 1) * 16 + l16] = m1; Pl[(pidx0 + 1) * 16 + l16] = l1; }
#undef STAGE
#undef SMPACK
}

// ---------------- kernel 3: combine KV-split partials (vectorized) ----------------
__global__ __launch_bounds__(64) void k_comb(const float* __restrict__ Pm,
                                             const float* __restrict__ Pl,
                                             const u16* __restrict__ PO,
                                             float* __restrict__ out) {
  const int qg = blockIdx.x;
  const int tid = threadIdx.x;

  __shared__ float sc[NSP][16];  // [split][row]
  if (tid < 16) {
    float m = -1e30f;
#pragma unroll
    for (int s = 0; s < NSP; ++s) m = fmaxf(m, Pm[(s * NQG + qg) * 16 + tid]);
    float den = 0.f;
#pragma unroll
    for (int s = 0; s < NSP; ++s) {
      float e = __expf(Pm[(s * NQG + qg) * 16 + tid] - m);
      sc[s][tid] = e;
      den += Pl[(s * NQG + qg) * 16 + tid] * e;
    }
    float inv = 1.0f / den;
#pragma unroll
    for (int s = 0; s < NSP; ++s) sc[s][tid] *= inv;
  }
  __syncthreads();

  float* op = out + (size_t)qg * 16 * DIM;
  for (int i = tid; i < 16 * DIM / 4; i += 64) {
    int row = (i * 4) >> 7;
    f32x4 a = (f32x4){0.f, 0.f, 0.f, 0.f};
#pragma unroll
    for (int s = 0; s < NSP; ++s) {
      u16x4 p = *(const u16x4*)(const void*)(PO + (size_t)(s * NQG + qg) * 16 * DIM + i * 4);
      float wgt = sc[s][row];
      a[0] += bu2f(p.x) * wgt;
      a[1] += bu2f(p.y) * wgt;
      a[2] += bu2f(p.z) * wgt;
      a[3] += bu2f(p.w) * wgt;
    }
    *(f32x4*)(op + i * 4) = a;
  }
}

extern "C" void kernel_launch(void* const* d_in, const int* in_sizes, int n_in,
                              void* d_out, int out_size, void* d_ws, size_t ws_size,
                              hipStream_t stream) {
  const float* X  = (const float*)d_in[0];
  const float* wq = (const float*)d_in[4];
  const float* wk = (const float*)d_in[5];
  const float* wv = (const float*)d_in[6];
  float* out = (float*)d_out;

  u16* WT = (u16*)d_ws;                       // 3*2*128*128 u16 = 192 KiB
  u16* Qh = WT + 3 * 2 * 128 * 128;
  u16* Ql = Qh + (size_t)BATCH * S_SRC * DIM; // 2 MiB each
  u16* Kh = Ql + (size_t)BATCH * S_SRC * DIM;
  u16* Kl = Kh + (size_t)BATCH * S_SRC * DIM;
  u16* VT = Kl + (size_t)BATCH * S_SRC * DIM; // [B][D][S]
  float* Pm = (float*)(VT + (size_t)BATCH * S_SRC * DIM);  // [NSP*NQG*16] f32
  float* Pl = Pm + (size_t)NSP * NQG * 16;
  u16* PO = (u16*)(Pl + (size_t)NSP * NQG * 16);           // [NSP*NQG*16*128] bf16 = 16 MiB

  hipLaunchKernelGGL(k_wsplit, dim3(192), dim3(256), 0, stream, wq, wk, wv, WT);
  hipLaunchKernelGGL(k_proj, dim3(3 * 256), dim3(256), 0, stream,
                     X, WT, Qh, Ql, Kh, Kl, VT);
  hipLaunchKernelGGL(k_attn, dim3(NQB * NSP), dim3(512), 0, stream,
                     Qh, Ql, Kh, Kl, VT, Pm, Pl, PO);
  hipLaunchKernelGGL(k_comb, dim3(NQG), dim3(64), 0, stream, Pm, Pl, PO, out);
}

// Round 12
// 72.232 us; speedup vs baseline: 1.7341x; 1.0042x over previous
//
#include <hip/hip_runtime.h>
#include <hip/hip_bf16.h>

#define S_SRC 4096
#define DIM 128
#define BATCH 2
#define NSP 8
#define NQB 32    // 256-row q-blocks
#define NQG 512   // 16-row q-groups total
#define NWIN 8    // (S_SRC/NSP)/64 key windows per split

typedef unsigned short u16;
typedef unsigned int u32;
typedef __bf16 bf16x8 __attribute__((ext_vector_type(8)));
typedef float f32x4 __attribute__((ext_vector_type(4)));
typedef u32 u32x4 __attribute__((ext_vector_type(4)));
typedef u16 u16x8 __attribute__((ext_vector_type(8)));

__device__ __forceinline__ __bf16 bf_hi(float x) { return (__bf16)x; }
__device__ __forceinline__ __bf16 bf_lo(float x, __bf16 h) { return (__bf16)(x - (float)h); }
__device__ __forceinline__ u16 bfu(__bf16 h) { return __builtin_bit_cast(u16, h); }
__device__ __forceinline__ u16 f2bu(float x) { return __builtin_bit_cast(u16, (__bf16)x); }
__device__ __forceinline__ float bu2f(u16 u) { return (float)__builtin_bit_cast(__bf16, u); }
__device__ __forceinline__ u32 pk2(float lo, float hi) {
  return (u32)f2bu(lo) | ((u32)f2bu(hi) << 16);
}
__device__ __forceinline__ void g2l16(const u16* src, u16* ldst) {
  __builtin_amdgcn_global_load_lds((const __attribute__((address_space(1))) void*)src,
                                   (__attribute__((address_space(3))) void*)ldst, 16, 0, 0);
}
#define MFMA __builtin_amdgcn_mfma_f32_16x16x32_bf16

// ---------------- kernel 0: transpose + hi/lo split the weight matrices ----------------
// Wq also folds log2(e)/sqrt(128) so all softmax exponentials run in base-2 (exp2).
__global__ __launch_bounds__(256) void k_wsplit(const float* __restrict__ wq,
                                                const float* __restrict__ wk,
                                                const float* __restrict__ wv,
                                                u16* __restrict__ wt) {
  int idx = blockIdx.x * 256 + threadIdx.x;  // 3*128*128 = 49152
  int mat = idx >> 14;
  int r = idx & 16383;
  int d = r >> 7, e = r & 127;
  const float* w = (mat == 0) ? wq : ((mat == 1) ? wk : wv);
  float x = w[r];
  if (mat == 0) x *= 0.12751744684693238f;  // log2(e) / sqrt(128)
  __bf16 h = bf_hi(x);
  __bf16 l = bf_lo(x, h);
  wt[((mat * 2 + 0) * 128 + e) * 128 + d] = bfu(h);
  wt[((mat * 2 + 1) * 128 + e) * 128 + d] = bfu(l);
}

// ---------------- kernel 1: QKV projection (fused 3 mats, X read once) ----------------
__global__ __launch_bounds__(256) void k_proj(const float* __restrict__ X,
                                              const u16* __restrict__ wt,
                                              u16* __restrict__ Qh, u16* __restrict__ Ql,
                                              u16* __restrict__ Kh, u16* __restrict__ Kl,
                                              u16* __restrict__ VT) {
  const int b = blockIdx.x >> 7;
  const int tile = blockIdx.x & 127;
  const int tid = threadIdx.x;
  const int w = tid >> 6, lane = tid & 63, g = lane >> 4, l16 = lane & 15;

  bf16x8 a_h[2][4], a_l[2][4];
#pragma unroll
  for (int mf = 0; mf < 2; ++mf) {
    int row = tile * 32 + mf * 16 + l16;
    const float* xr = X + ((size_t)b * S_SRC + row) * DIM;
#pragma unroll
    for (int kf = 0; kf < 4; ++kf) {
      int d0 = kf * 32 + g * 8;
      f32x4 x0 = *(const f32x4*)(xr + d0);
      f32x4 x1 = *(const f32x4*)(xr + d0 + 4);
#pragma unroll
      for (int j = 0; j < 4; ++j) {
        __bf16 h0 = bf_hi(x0[j]);
        __bf16 h1 = bf_hi(x1[j]);
        a_h[mf][kf][j] = h0;
        a_l[mf][kf][j] = bf_lo(x0[j], h0);
        a_h[mf][kf][4 + j] = h1;
        a_l[mf][kf][4 + j] = bf_lo(x1[j], h1);
      }
    }
  }

#pragma unroll
  for (int mat = 0; mat < 3; ++mat) {
    const u16* wth = wt + (mat * 2 + 0) * 16384;
    const u16* wtl = wt + (mat * 2 + 1) * 16384;
#pragma unroll
    for (int nf = 0; nf < 2; ++nf) {
      int col = w * 32 + nf * 16 + l16;
      f32x4 acc[2];
      acc[0] = (f32x4){0.f, 0.f, 0.f, 0.f};
      acc[1] = (f32x4){0.f, 0.f, 0.f, 0.f};
#pragma unroll
      for (int kf = 0; kf < 4; ++kf) {
        int d0 = kf * 32 + g * 8;
        bf16x8 bh = *(const bf16x8*)(const void*)(wth + col * 128 + d0);
        bf16x8 bl = *(const bf16x8*)(const void*)(wtl + col * 128 + d0);
#pragma unroll
        for (int mf = 0; mf < 2; ++mf) {
          acc[mf] = MFMA(a_h[mf][kf], bh, acc[mf], 0, 0, 0);
          acc[mf] = MFMA(a_h[mf][kf], bl, acc[mf], 0, 0, 0);
          acc[mf] = MFMA(a_l[mf][kf], bh, acc[mf], 0, 0, 0);
        }
      }
#pragma unroll
      for (int mf = 0; mf < 2; ++mf)
#pragma unroll
        for (int r = 0; r < 4; ++r) {
          int row = tile * 32 + mf * 16 + g * 4 + r;
          float v = acc[mf][r];
          if (mat == 2) {
            VT[((size_t)b * DIM + col) * S_SRC + row] = f2bu(v);
          } else {
            __bf16 h = bf_hi(v);
            __bf16 l = bf_lo(v, h);
            size_t o = ((size_t)b * S_SRC + row) * DIM + col;
            if (mat == 0) { Qh[o] = bfu(h); Ql[o] = bfu(l); }
            else          { Kh[o] = bfu(h); Kl[o] = bfu(l); }
          }
        }
    }
  }
}

// ---------------- kernel 2: flash attention, 64-key windows, 3-deep ring ----------------
// Swapped QK^T (A=K, B=Q). Per wave: 2 q-groups of 16 rows. 8 windows of 64 keys.
// Scores are in log2 domain (log2e folded into Wq); all exponentials are exp2.
__global__ __launch_bounds__(512, 2) void k_attn(const u16* __restrict__ Qh, const u16* __restrict__ Ql,
                                                 const u16* __restrict__ Kh, const u16* __restrict__ Kl,
                                                 const u16* __restrict__ VT,
                                                 float* __restrict__ Pm, float* __restrict__ Pl,
                                                 u16* __restrict__ PO) {
  const int bid = blockIdx.x;
  const int sp = bid & 7;     // kv split 0..7 (== XCD id)
  const int qb = bid >> 3;    // 256-row q-block 0..31
  const int b = qb >> 4;
  const int tid = threadIdx.x;
  const int w = tid >> 6, lane = tid & 63, g = lane >> 4, l16 = lane & 15;

  __shared__ alignas(16) u16 kbuf[3][16384];  // 96KB: [hi 64x128 | lo 64x128] chunk-swizzled
  __shared__ alignas(16) u16 vbuf[3][8192];   // 48KB: [128d x 64s] chunk-swizzled

  // ---- Q fragments (hi/lo), 32 q-rows: 2 groups of 16 ----
  const int gr0 = qb * 256 + w * 32;
  bf16x8 qh0[4], ql0[4], qh1[4], ql1[4];
  {
    const u16* p0h = Qh + ((size_t)gr0 + l16) * DIM;
    const u16* p0l = Ql + ((size_t)gr0 + l16) * DIM;
    const u16* p1h = Qh + ((size_t)gr0 + 16 + l16) * DIM;
    const u16* p1l = Ql + ((size_t)gr0 + 16 + l16) * DIM;
#pragma unroll
    for (int kf = 0; kf < 4; ++kf) {
      int d0 = kf * 32 + g * 8;
      qh0[kf] = *(const bf16x8*)(const void*)(p0h + d0);
      ql0[kf] = *(const bf16x8*)(const void*)(p0l + d0);
      qh1[kf] = *(const bf16x8*)(const void*)(p1h + d0);
      ql1[kf] = *(const bf16x8*)(const void*)(p1l + d0);
    }
  }

  f32x4 acc0[8], acc1[8];
#pragma unroll
  for (int nf = 0; nf < 8; ++nf) {
    acc0[nf] = (f32x4){0.f, 0.f, 0.f, 0.f};
    acc1[nf] = (f32x4){0.f, 0.f, 0.f, 0.f};
  }
  float m0 = -1e30f, m1 = -1e30f, l0 = 0.f, l1 = 0.f;

  const int key_base = sp * (S_SRC / NSP);
  const u16* KhB = Kh + (size_t)b * S_SRC * DIM;
  const u16* KlB = Kl + (size_t)b * S_SRC * DIM;
  const u16* VTB = VT + (size_t)b * DIM * S_SRC;

  // staging (512 threads x 6 chunks of 16B), chunk-XOR swizzle
  const int kkey0 = tid >> 4;                           // key row 0..31 (pass0); +32 pass1
  const int kks = ((tid & 15) ^ (kkey0 & 15)) << 3;     // swizzled source d-offset (elems)
  const int vd0 = tid >> 3;                             // V d-row 0..63 (pass0); +64 pass1
  const int vks = ((tid & 7) ^ ((vd0 >> 1) & 7)) << 3;  // swizzled source s-offset (elems)
  const int wb = w * 512;                               // wave-uniform LDS chunk base (u16)
  const int mg = ((g & 1) << 1) | (g >> 1);             // V key-chunk permutation {0,2,1,3}

#define STAGE(BUF, KEY0)                                                             \
  {                                                                                  \
    g2l16(KhB + ((size_t)((KEY0) + kkey0)) * DIM + kks,      &kbuf[BUF][wb]);        \
    g2l16(KhB + ((size_t)((KEY0) + 32 + kkey0)) * DIM + kks, &kbuf[BUF][4096 + wb]); \
    g2l16(KlB + ((size_t)((KEY0) + kkey0)) * DIM + kks,      &kbuf[BUF][8192 + wb]); \
    g2l16(KlB + ((size_t)((KEY0) + 32 + kkey0)) * DIM + kks, &kbuf[BUF][12288 + wb]);\
    g2l16(VTB + (size_t)vd0 * S_SRC + (KEY0) + vks,          &vbuf[BUF][wb]);        \
    g2l16(VTB + (size_t)(64 + vd0) * S_SRC + (KEY0) + vks,   &vbuf[BUF][4096 + wb]); \
  }

// S = f32x4[4] score array (keys st*16 + g*4 + r of q-col l16), MR/LR running stats,
// ACC = f32x4[8] output acc, PA/PB = packed P A-frags for key-chunks 0/1.
#define SMPACK(S, MR, LR, ACC, PA, PB)                                               \
  {                                                                                  \
    float mxa = fmaxf(fmaxf(fmaxf(S[0][0], S[0][1]), fmaxf(S[0][2], S[0][3])),       \
                      fmaxf(fmaxf(S[1][0], S[1][1]), fmaxf(S[1][2], S[1][3])));      \
    float mxb = fmaxf(fmaxf(fmaxf(S[2][0], S[2][1]), fmaxf(S[2][2], S[2][3])),       \
                      fmaxf(fmaxf(S[3][0], S[3][1]), fmaxf(S[3][2], S[3][3])));      \
    float mx = fmaxf(mxa, mxb);                                                      \
    mx = fmaxf(mx, __shfl_xor(mx, 16, 64));                                          \
    mx = fmaxf(mx, __shfl_xor(mx, 32, 64));                                          \
    if (!__all(mx - MR <= 11.5f)) {                                                  \
      float mn = fmaxf(MR, mx);                                                      \
      float f = exp2f(MR - mn);                                                      \
      LR *= f; MR = mn;                                                              \
      float fr0 = __shfl(f, g * 4 + 0, 64);                                          \
      float fr1 = __shfl(f, g * 4 + 1, 64);                                          \
      float fr2 = __shfl(f, g * 4 + 2, 64);                                          \
      float fr3 = __shfl(f, g * 4 + 3, 64);                                          \
      _Pragma("unroll")                                                              \
      for (int nf = 0; nf < 8; ++nf) {                                               \
        ACC[nf][0] *= fr0; ACC[nf][1] *= fr1;                                        \
        ACC[nf][2] *= fr2; ACC[nf][3] *= fr3;                                        \
      }                                                                              \
    }                                                                                \
    float e0 = exp2f(S[0][0] - MR), e1 = exp2f(S[0][1] - MR);                        \
    float e2 = exp2f(S[0][2] - MR), e3 = exp2f(S[0][3] - MR);                        \
    float e4 = exp2f(S[1][0] - MR), e5 = exp2f(S[1][1] - MR);                        \
    float e6 = exp2f(S[1][2] - MR), e7 = exp2f(S[1][3] - MR);                        \
    float f0 = exp2f(S[2][0] - MR), f1 = exp2f(S[2][1] - MR);                        \
    float f2 = exp2f(S[2][2] - MR), f3 = exp2f(S[2][3] - MR);                        \
    float f4 = exp2f(S[3][0] - MR), f5 = exp2f(S[3][1] - MR);                        \
    float f6 = exp2f(S[3][2] - MR), f7 = exp2f(S[3][3] - MR);                        \
    float sm = (((e0 + e1) + (e2 + e3)) + ((e4 + e5) + (e6 + e7)))                   \
             + (((f0 + f1) + (f2 + f3)) + ((f4 + f5) + (f6 + f7)));                  \
    sm += __shfl_xor(sm, 16, 64);                                                    \
    sm += __shfl_xor(sm, 32, 64);                                                    \
    LR += sm;                                                                        \
    bool odd = (g & 1);                                                              \
    {                                                                                \
      u32 w0 = pk2(e0, e1), w1 = pk2(e2, e3), w2 = pk2(e4, e5), w3 = pk2(e6, e7);    \
      u32 x0 = __shfl_xor(w0, 16, 64), x1 = __shfl_xor(w1, 16, 64);                  \
      u32 x2 = __shfl_xor(w2, 16, 64), x3 = __shfl_xor(w3, 16, 64);                  \
      u32x4 pw;                                                                      \
      pw.x = odd ? x2 : w0; pw.y = odd ? x3 : w1;                                    \
      pw.z = odd ? w2 : x0; pw.w = odd ? w3 : x1;                                    \
      PA = __builtin_bit_cast(bf16x8, pw);                                           \
    }                                                                                \
    {                                                                                \
      u32 w0 = pk2(f0, f1), w1 = pk2(f2, f3), w2 = pk2(f4, f5), w3 = pk2(f6, f7);    \
      u32 x0 = __shfl_xor(w0, 16, 64), x1 = __shfl_xor(w1, 16, 64);                  \
      u32 x2 = __shfl_xor(w2, 16, 64), x3 = __shfl_xor(w3, 16, 64);                  \
      u32x4 pw;                                                                      \
      pw.x = odd ? x2 : w0; pw.y = odd ? x3 : w1;                                    \
      pw.z = odd ? w2 : x0; pw.w = odd ? w3 : x1;                                    \
      PB = __builtin_bit_cast(bf16x8, pw);                                           \
    }                                                                                \
  }

  // ---- prologue: stage tiles 0,1 (12 loads in flight) ----
  STAGE(0, key_base)
  STAGE(1, key_base + 64)

  int cur = 0;  // ring buffer holding tile i
  for (int i = 0; i < NWIN; ++i) {
    if (i < NWIN - 1) {
      asm volatile("s_waitcnt vmcnt(6)" ::: "memory");  // tile i landed; tile i+1 in flight
    } else {
      asm volatile("s_waitcnt vmcnt(0)" ::: "memory");
    }
    __builtin_amdgcn_s_barrier();  // all waves' tile-i DMAs + prior-window reads done
    if (i + 2 < NWIN) {
      int nx = cur + 2; nx = (nx >= 3) ? nx - 3 : nx;
      STAGE(nx, key_base + (i + 2) * 64)
    }

    const u16* kb = kbuf[cur];
    const u16* vb = vbuf[cur];

    // ---- QK^T swapped, 64 keys x 32 q-rows: each K-frag read feeds both q-groups ----
    f32x4 sg0[4], sg1[4];
#pragma unroll
    for (int st = 0; st < 4; ++st) {
      sg0[st] = (f32x4){0.f, 0.f, 0.f, 0.f};
      sg1[st] = (f32x4){0.f, 0.f, 0.f, 0.f};
    }
    __builtin_amdgcn_s_setprio(1);
#pragma unroll
    for (int kf = 0; kf < 4; ++kf) {
      int cs = ((kf * 4 + g) ^ l16) << 3;
#pragma unroll
      for (int st = 0; st < 4; ++st) {
        const u16* kp = kb + (st * 16 + l16) * 128 + cs;
        bf16x8 kh = *(const bf16x8*)(const void*)kp;
        bf16x8 kl = *(const bf16x8*)(const void*)(kp + 8192);
        sg0[st] = MFMA(kh, qh0[kf], sg0[st], 0, 0, 0);
        sg0[st] = MFMA(kh, ql0[kf], sg0[st], 0, 0, 0);
        sg0[st] = MFMA(kl, qh0[kf], sg0[st], 0, 0, 0);
        sg1[st] = MFMA(kh, qh1[kf], sg1[st], 0, 0, 0);
        sg1[st] = MFMA(kh, ql1[kf], sg1[st], 0, 0, 0);
        sg1[st] = MFMA(kl, qh1[kf], sg1[st], 0, 0, 0);
      }
    }
    __builtin_amdgcn_s_setprio(0);

    // ---- softmax + P-pack, one chain per group per 64 keys ----
    bf16x8 pa0A, pa0B, pa1A, pa1B;
    SMPACK(sg0, m0, l0, acc0, pa0A, pa0B)
    SMPACK(sg1, m1, l1, acc1, pa1A, pa1B)

    // ---- PV: one V-frag pair feeds both q-groups ----
    __builtin_amdgcn_s_setprio(1);
#pragma unroll
    for (int nf = 0; nf < 8; ++nf) {
      int d = nf * 16 + l16;
      int sw = (d >> 1) & 7;
      const u16* vr = vb + d * 64;
      bf16x8 vf0 = *(const bf16x8*)(const void*)(vr + ((mg ^ sw) << 3));
      bf16x8 vf1 = *(const bf16x8*)(const void*)(vr + (((4 + mg) ^ sw) << 3));
      acc0[nf] = MFMA(pa0A, vf0, acc0[nf], 0, 0, 0);
      acc0[nf] = MFMA(pa0B, vf1, acc0[nf], 0, 0, 0);
      acc1[nf] = MFMA(pa1A, vf0, acc1[nf], 0, 0, 0);
      acc1[nf] = MFMA(pa1B, vf1, acc1[nf], 0, 0, 0);
    }
    __builtin_amdgcn_s_setprio(0);

    cur = (cur + 1 >= 3) ? cur - 2 : cur + 1;
  }

  // ---- write partials (m, l, O) for the 2 16-row groups ----
  const int pidx0 = sp * NQG + (gr0 >> 4);
  {
    u16* po = PO + (size_t)pidx0 * 16 * DIM;
#pragma unroll
    for (int nf = 0; nf < 8; ++nf)
#pragma unroll
      for (int r = 0; r < 4; ++r)
        po[(g * 4 + r) * DIM + nf * 16 + l16] = f2bu(acc0[nf][r]);
    u16* po1 = PO + (size_t)(pidx0 + 1) * 16 * DIM;
#pragma unroll
    for (int nf = 0; nf < 8; ++nf)
#pragma unroll
      for (int r = 0; r < 4; ++r)
        po1[(g * 4 + r) * DIM + nf * 16 + l16] = f2bu(acc1[nf][r]);
  }
  if (g == 0) { Pm[pidx0 * 16 + l16] = m0; Pl[pidx0 * 16 + l16] = l0; }
  if (g == 1) { Pm[(pidx0 + 1) * 16 + l16] = m1; Pl[(pidx0 + 1) * 16 + l16] = l1; }
#undef STAGE
#undef SMPACK
}

// ---------------- kernel 3: combine KV-split partials (wide loads, 256 thr) ----------------
__global__ __launch_bounds__(256) void k_comb(const float* __restrict__ Pm,
                                              const float* __restrict__ Pl,
                                              const u16* __restrict__ PO,
                                              float* __restrict__ out) {
  const int qg = blockIdx.x;
  const int tid = threadIdx.x;

  __shared__ float sc[NSP][16];  // [split][row]
  if (tid < 16) {
    float m = -1e30f;
#pragma unroll
    for (int s = 0; s < NSP; ++s) m = fmaxf(m, Pm[(s * NQG + qg) * 16 + tid]);
    float den = 0.f;
#pragma unroll
    for (int s = 0; s < NSP; ++s) {
      float e = exp2f(Pm[(s * NQG + qg) * 16 + tid] - m);  // log2-domain stats
      sc[s][tid] = e;
      den += Pl[(s * NQG + qg) * 16 + tid] * e;
    }
    float inv = 1.0f / den;
#pragma unroll
    for (int s = 0; s < NSP; ++s) sc[s][tid] *= inv;
  }
  __syncthreads();

  // 2048 elems / 256 thr = 8 per thread (one u16x8 per split, two f32x4 stores)
  const int e0 = tid * 8;
  const int row = e0 >> 7;
  float a[8];
#pragma unroll
  for (int j = 0; j < 8; ++j) a[j] = 0.f;
#pragma unroll
  for (int s = 0; s < NSP; ++s) {
    u16x8 p = *(const u16x8*)(const void*)(PO + (size_t)(s * NQG + qg) * 16 * DIM + e0);
    float wgt = sc[s][row];
#pragma unroll
    for (int j = 0; j < 8; ++j) a[j] += bu2f(p[j]) * wgt;
  }
  float* op = out + (size_t)qg * 16 * DIM + e0;
  f32x4 o0 = {a[0], a[1], a[2], a[3]};
  f32x4 o1 = {a[4], a[5], a[6], a[7]};
  *(f32x4*)op = o0;
  *(f32x4*)(op + 4) = o1;
}

extern "C" void kernel_launch(void* const* d_in, const int* in_sizes, int n_in,
                              void* d_out, int out_size, void* d_ws, size_t ws_size,
                              hipStream_t stream) {
  const float* X  = (const float*)d_in[0];
  const float* wq = (const float*)d_in[4];
  const float* wk = (const float*)d_in[5];
  const float* wv = (const float*)d_in[6];
  float* out = (float*)d_out;

  u16* WT = (u16*)d_ws;                       // 3*2*128*128 u16 = 192 KiB
  u16* Qh = WT + 3 * 2 * 128 * 128;
  u16* Ql = Qh + (size_t)BATCH * S_SRC * DIM; // 2 MiB each
  u16* Kh = Ql + (size_t)BATCH * S_SRC * DIM;
  u16* Kl = Kh + (size_t)BATCH * S_SRC * DIM;
  u16* VT = Kl + (size_t)BATCH * S_SRC * DIM; // [B][D][S]
  float* Pm = (float*)(VT + (size_t)BATCH * S_SRC * DIM);  // [NSP*NQG*16] f32
  float* Pl = Pm + (size_t)NSP * NQG * 16;
  u16* PO = (u16*)(Pl + (size_t)NSP * NQG * 16);           // [NSP*NQG*16*128] bf16 = 16 MiB

  hipLaunchKernelGGL(k_wsplit, dim3(192), dim3(256), 0, stream, wq, wk, wv, WT);
  hipLaunchKernelGGL(k_proj, dim3(BATCH * S_SRC / 32), dim3(256), 0, stream,
                     X, WT, Qh, Ql, Kh, Kl, VT);
  hipLaunchKernelGGL(k_attn, dim3(NQB * NSP), dim3(512), 0, stream,
                     Qh, Ql, Kh, Kl, VT, Pm, Pl, PO);
  hipLaunchKernelGGL(k_comb, dim3(NQG), dim3(256), 0, stream, Pm, Pl, PO, out);
}

// Round 13
// 68.046 us; speedup vs baseline: 1.8408x; 1.0615x over previous
//
#include <hip/hip_runtime.h>
#include <hip/hip_bf16.h>

#define S_SRC 4096
#define DIM 128
#define BATCH 2
#define NSP 8
#define NQB 32    // 256-row q-blocks
#define NQG 512   // 16-row q-groups total
#define NWIN 8    // (S_SRC/NSP)/64 key windows per split

typedef unsigned short u16;
typedef unsigned int u32;
typedef __bf16 bf16x8 __attribute__((ext_vector_type(8)));
typedef float f32x4 __attribute__((ext_vector_type(4)));
typedef u32 u32x4 __attribute__((ext_vector_type(4)));
typedef u16 u16x8 __attribute__((ext_vector_type(8)));

__device__ __forceinline__ __bf16 bf_hi(float x) { return (__bf16)x; }
__device__ __forceinline__ __bf16 bf_lo(float x, __bf16 h) { return (__bf16)(x - (float)h); }
__device__ __forceinline__ u16 bfu(__bf16 h) { return __builtin_bit_cast(u16, h); }
__device__ __forceinline__ u16 f2bu(float x) { return __builtin_bit_cast(u16, (__bf16)x); }
__device__ __forceinline__ float bu2f(u16 u) { return (float)__builtin_bit_cast(__bf16, u); }
__device__ __forceinline__ u32 pk2(float lo, float hi) {
  return (u32)f2bu(lo) | ((u32)f2bu(hi) << 16);
}
// native exp2: v_exp_f32 IS 2^x on AMD — single TRANS instruction, no pre-multiply
__device__ __forceinline__ float ex2(float x) {
  float r;
  asm("v_exp_f32 %0, %1" : "=v"(r) : "v"(x));
  return r;
}
__device__ __forceinline__ void g2l16(const u16* src, u16* ldst) {
  __builtin_amdgcn_global_load_lds((const __attribute__((address_space(1))) void*)src,
                                   (__attribute__((address_space(3))) void*)ldst, 16, 0, 0);
}
#define MFMA __builtin_amdgcn_mfma_f32_16x16x32_bf16

// ---------------- kernel 0: transpose + hi/lo split the weight matrices ----------------
// Wq also folds log2(e)/sqrt(128) so all softmax exponentials run in base-2 (v_exp_f32).
__global__ __launch_bounds__(256) void k_wsplit(const float* __restrict__ wq,
                                                const float* __restrict__ wk,
                                                const float* __restrict__ wv,
                                                u16* __restrict__ wt) {
  int idx = blockIdx.x * 256 + threadIdx.x;  // 3*128*128 = 49152
  int mat = idx >> 14;
  int r = idx & 16383;
  int d = r >> 7, e = r & 127;
  const float* w = (mat == 0) ? wq : ((mat == 1) ? wk : wv);
  float x = w[r];
  if (mat == 0) x *= 0.12751744684693238f;  // log2(e) / sqrt(128)
  __bf16 h = bf_hi(x);
  __bf16 l = bf_lo(x, h);
  wt[((mat * 2 + 0) * 128 + e) * 128 + d] = bfu(h);
  wt[((mat * 2 + 1) * 128 + e) * 128 + d] = bfu(l);
}

// ---------------- kernel 1: QKV projection (fused 3 mats, X read once) ----------------
__global__ __launch_bounds__(256) void k_proj(const float* __restrict__ X,
                                              const u16* __restrict__ wt,
                                              u16* __restrict__ Qh, u16* __restrict__ Ql,
                                              u16* __restrict__ Kh, u16* __restrict__ Kl,
                                              u16* __restrict__ VT) {
  const int b = blockIdx.x >> 7;
  const int tile = blockIdx.x & 127;
  const int tid = threadIdx.x;
  const int w = tid >> 6, lane = tid & 63, g = lane >> 4, l16 = lane & 15;

  bf16x8 a_h[2][4], a_l[2][4];
#pragma unroll
  for (int mf = 0; mf < 2; ++mf) {
    int row = tile * 32 + mf * 16 + l16;
    const float* xr = X + ((size_t)b * S_SRC + row) * DIM;
#pragma unroll
    for (int kf = 0; kf < 4; ++kf) {
      int d0 = kf * 32 + g * 8;
      f32x4 x0 = *(const f32x4*)(xr + d0);
      f32x4 x1 = *(const f32x4*)(xr + d0 + 4);
#pragma unroll
      for (int j = 0; j < 4; ++j) {
        __bf16 h0 = bf_hi(x0[j]);
        __bf16 h1 = bf_hi(x1[j]);
        a_h[mf][kf][j] = h0;
        a_l[mf][kf][j] = bf_lo(x0[j], h0);
        a_h[mf][kf][4 + j] = h1;
        a_l[mf][kf][4 + j] = bf_lo(x1[j], h1);
      }
    }
  }

#pragma unroll
  for (int mat = 0; mat < 3; ++mat) {
    const u16* wth = wt + (mat * 2 + 0) * 16384;
    const u16* wtl = wt + (mat * 2 + 1) * 16384;
#pragma unroll
    for (int nf = 0; nf < 2; ++nf) {
      int col = w * 32 + nf * 16 + l16;
      f32x4 acc[2];
      acc[0] = (f32x4){0.f, 0.f, 0.f, 0.f};
      acc[1] = (f32x4){0.f, 0.f, 0.f, 0.f};
#pragma unroll
      for (int kf = 0; kf < 4; ++kf) {
        int d0 = kf * 32 + g * 8;
        bf16x8 bh = *(const bf16x8*)(const void*)(wth + col * 128 + d0);
        bf16x8 bl = *(const bf16x8*)(const void*)(wtl + col * 128 + d0);
#pragma unroll
        for (int mf = 0; mf < 2; ++mf) {
          acc[mf] = MFMA(a_h[mf][kf], bh, acc[mf], 0, 0, 0);
          acc[mf] = MFMA(a_h[mf][kf], bl, acc[mf], 0, 0, 0);
          acc[mf] = MFMA(a_l[mf][kf], bh, acc[mf], 0, 0, 0);
        }
      }
#pragma unroll
      for (int mf = 0; mf < 2; ++mf)
#pragma unroll
        for (int r = 0; r < 4; ++r) {
          int row = tile * 32 + mf * 16 + g * 4 + r;
          float v = acc[mf][r];
          if (mat == 2) {
            VT[((size_t)b * DIM + col) * S_SRC + row] = f2bu(v);
          } else {
            __bf16 h = bf_hi(v);
            __bf16 l = bf_lo(v, h);
            size_t o = ((size_t)b * S_SRC + row) * DIM + col;
            if (mat == 0) { Qh[o] = bfu(h); Ql[o] = bfu(l); }
            else          { Kh[o] = bfu(h); Kl[o] = bfu(l); }
          }
        }
    }
  }
}

// ---------------- kernel 2: flash attention, 64-key windows, 3-deep ring ----------------
// Swapped QK^T (A=K, B=Q). Per wave: 2 q-groups of 16 rows. 8 windows of 64 keys.
// Scores are in log2 domain (log2e folded into Wq); all exponentials are v_exp_f32.
__global__ __launch_bounds__(512, 2) void k_attn(const u16* __restrict__ Qh, const u16* __restrict__ Ql,
                                                 const u16* __restrict__ Kh, const u16* __restrict__ Kl,
                                                 const u16* __restrict__ VT,
                                                 float* __restrict__ Pm, float* __restrict__ Pl,
                                                 u16* __restrict__ PO) {
  const int bid = blockIdx.x;
  const int sp = bid & 7;     // kv split 0..7 (== XCD id)
  const int qb = bid >> 3;    // 256-row q-block 0..31
  const int b = qb >> 4;
  const int tid = threadIdx.x;
  const int w = tid >> 6, lane = tid & 63, g = lane >> 4, l16 = lane & 15;

  __shared__ alignas(16) u16 kbuf[3][16384];  // 96KB: [hi 64x128 | lo 64x128] chunk-swizzled
  __shared__ alignas(16) u16 vbuf[3][8192];   // 48KB: [128d x 64s] chunk-swizzled

  // ---- Q fragments (hi/lo), 32 q-rows: 2 groups of 16 ----
  const int gr0 = qb * 256 + w * 32;
  bf16x8 qh0[4], ql0[4], qh1[4], ql1[4];
  {
    const u16* p0h = Qh + ((size_t)gr0 + l16) * DIM;
    const u16* p0l = Ql + ((size_t)gr0 + l16) * DIM;
    const u16* p1h = Qh + ((size_t)gr0 + 16 + l16) * DIM;
    const u16* p1l = Ql + ((size_t)gr0 + 16 + l16) * DIM;
#pragma unroll
    for (int kf = 0; kf < 4; ++kf) {
      int d0 = kf * 32 + g * 8;
      qh0[kf] = *(const bf16x8*)(const void*)(p0h + d0);
      ql0[kf] = *(const bf16x8*)(const void*)(p0l + d0);
      qh1[kf] = *(const bf16x8*)(const void*)(p1h + d0);
      ql1[kf] = *(const bf16x8*)(const void*)(p1l + d0);
    }
  }

  f32x4 acc0[8], acc1[8];
#pragma unroll
  for (int nf = 0; nf < 8; ++nf) {
    acc0[nf] = (f32x4){0.f, 0.f, 0.f, 0.f};
    acc1[nf] = (f32x4){0.f, 0.f, 0.f, 0.f};
  }
  float m0 = -1e30f, m1 = -1e30f, l0 = 0.f, l1 = 0.f;

  const int key_base = sp * (S_SRC / NSP);
  const u16* KhB = Kh + (size_t)b * S_SRC * DIM;
  const u16* KlB = Kl + (size_t)b * S_SRC * DIM;
  const u16* VTB = VT + (size_t)b * DIM * S_SRC;

  // staging (512 threads x 6 chunks of 16B), chunk-XOR swizzle
  const int kkey0 = tid >> 4;                           // key row 0..31 (pass0); +32 pass1
  const int kks = ((tid & 15) ^ (kkey0 & 15)) << 3;     // swizzled source d-offset (elems)
  const int vd0 = tid >> 3;                             // V d-row 0..63 (pass0); +64 pass1
  const int vks = ((tid & 7) ^ ((vd0 >> 1) & 7)) << 3;  // swizzled source s-offset (elems)
  const int wb = w * 512;                               // wave-uniform LDS chunk base (u16)
  const int mg = ((g & 1) << 1) | (g >> 1);             // V key-chunk permutation {0,2,1,3}

#define STAGE(BUF, KEY0)                                                             \
  {                                                                                  \
    g2l16(KhB + ((size_t)((KEY0) + kkey0)) * DIM + kks,      &kbuf[BUF][wb]);        \
    g2l16(KhB + ((size_t)((KEY0) + 32 + kkey0)) * DIM + kks, &kbuf[BUF][4096 + wb]); \
    g2l16(KlB + ((size_t)((KEY0) + kkey0)) * DIM + kks,      &kbuf[BUF][8192 + wb]); \
    g2l16(KlB + ((size_t)((KEY0) + 32 + kkey0)) * DIM + kks, &kbuf[BUF][12288 + wb]);\
    g2l16(VTB + (size_t)vd0 * S_SRC + (KEY0) + vks,          &vbuf[BUF][wb]);        \
    g2l16(VTB + (size_t)(64 + vd0) * S_SRC + (KEY0) + vks,   &vbuf[BUF][4096 + wb]); \
  }

// S = f32x4[4] score array (keys st*16 + g*4 + r of q-col l16), MR/LR running stats,
// ACC = f32x4[8] output acc, PA/PB = packed P A-frags for key-chunks 0/1.
#define SMPACK(S, MR, LR, ACC, PA, PB)                                               \
  {                                                                                  \
    float mxa = fmaxf(fmaxf(fmaxf(S[0][0], S[0][1]), fmaxf(S[0][2], S[0][3])),       \
                      fmaxf(fmaxf(S[1][0], S[1][1]), fmaxf(S[1][2], S[1][3])));      \
    float mxb = fmaxf(fmaxf(fmaxf(S[2][0], S[2][1]), fmaxf(S[2][2], S[2][3])),       \
                      fmaxf(fmaxf(S[3][0], S[3][1]), fmaxf(S[3][2], S[3][3])));      \
    float mx = fmaxf(mxa, mxb);                                                      \
    mx = fmaxf(mx, __shfl_xor(mx, 16, 64));                                          \
    mx = fmaxf(mx, __shfl_xor(mx, 32, 64));                                          \
    if (!__all(mx - MR <= 11.5f)) {                                                  \
      float mn = fmaxf(MR, mx);                                                      \
      float f = ex2(MR - mn);                                                        \
      LR *= f; MR = mn;                                                              \
      float fr0 = __shfl(f, g * 4 + 0, 64);                                          \
      float fr1 = __shfl(f, g * 4 + 1, 64);                                          \
      float fr2 = __shfl(f, g * 4 + 2, 64);                                          \
      float fr3 = __shfl(f, g * 4 + 3, 64);                                          \
      _Pragma("unroll")                                                              \
      for (int nf = 0; nf < 8; ++nf) {                                               \
        ACC[nf][0] *= fr0; ACC[nf][1] *= fr1;                                        \
        ACC[nf][2] *= fr2; ACC[nf][3] *= fr3;                                        \
      }                                                                              \
    }                                                                                \
    float e0 = ex2(S[0][0] - MR), e1 = ex2(S[0][1] - MR);                            \
    float e2 = ex2(S[0][2] - MR), e3 = ex2(S[0][3] - MR);                            \
    float e4 = ex2(S[1][0] - MR), e5 = ex2(S[1][1] - MR);                            \
    float e6 = ex2(S[1][2] - MR), e7 = ex2(S[1][3] - MR);                            \
    float f0 = ex2(S[2][0] - MR), f1 = ex2(S[2][1] - MR);                            \
    float f2 = ex2(S[2][2] - MR), f3 = ex2(S[2][3] - MR);                            \
    float f4 = ex2(S[3][0] - MR), f5 = ex2(S[3][1] - MR);                            \
    float f6 = ex2(S[3][2] - MR), f7 = ex2(S[3][3] - MR);                            \
    float sm = (((e0 + e1) + (e2 + e3)) + ((e4 + e5) + (e6 + e7)))                   \
             + (((f0 + f1) + (f2 + f3)) + ((f4 + f5) + (f6 + f7)));                  \
    sm += __shfl_xor(sm, 16, 64);                                                    \
    sm += __shfl_xor(sm, 32, 64);                                                    \
    LR += sm;                                                                        \
    bool odd = (g & 1);                                                              \
    {                                                                                \
      u32 w0 = pk2(e0, e1), w1 = pk2(e2, e3), w2 = pk2(e4, e5), w3 = pk2(e6, e7);    \
      u32 x0 = __shfl_xor(w0, 16, 64), x1 = __shfl_xor(w1, 16, 64);                  \
      u32 x2 = __shfl_xor(w2, 16, 64), x3 = __shfl_xor(w3, 16, 64);                  \
      u32x4 pw;                                                                      \
      pw.x = odd ? x2 : w0; pw.y = odd ? x3 : w1;                                    \
      pw.z = odd ? w2 : x0; pw.w = odd ? w3 : x1;                                    \
      PA = __builtin_bit_cast(bf16x8, pw);                                           \
    }                                                                                \
    {                                                                                \
      u32 w0 = pk2(f0, f1), w1 = pk2(f2, f3), w2 = pk2(f4, f5), w3 = pk2(f6, f7);    \
      u32 x0 = __shfl_xor(w0, 16, 64), x1 = __shfl_xor(w1, 16, 64);                  \
      u32 x2 = __shfl_xor(w2, 16, 64), x3 = __shfl_xor(w3, 16, 64);                  \
      u32x4 pw;                                                                      \
      pw.x = odd ? x2 : w0; pw.y = odd ? x3 : w1;                                    \
      pw.z = odd ? w2 : x0; pw.w = odd ? w3 : x1;                                    \
      PB = __builtin_bit_cast(bf16x8, pw);                                           \
    }                                                                                \
  }

  // ---- prologue: stage tiles 0,1 (12 loads in flight) ----
  STAGE(0, key_base)
  STAGE(1, key_base + 64)

  int cur = 0;  // ring buffer holding tile i
  for (int i = 0; i < NWIN; ++i) {
    if (i < NWIN - 1) {
      asm volatile("s_waitcnt vmcnt(6)" ::: "memory");  // tile i landed; tile i+1 in flight
    } else {
      asm volatile("s_waitcnt vmcnt(0)" ::: "memory");
    }
    __builtin_amdgcn_s_barrier();  // all waves' tile-i DMAs + prior-window reads done
    if (i + 2 < NWIN) {
      int nx = cur + 2; nx = (nx >= 3) ? nx - 3 : nx;
      STAGE(nx, key_base + (i + 2) * 64)
    }

    const u16* kb = kbuf[cur];
    const u16* vb = vbuf[cur];

    // ---- QK^T swapped, 64 keys x 32 q-rows: each K-frag read feeds both q-groups ----
    f32x4 sg0[4], sg1[4];
#pragma unroll
    for (int st = 0; st < 4; ++st) {
      sg0[st] = (f32x4){0.f, 0.f, 0.f, 0.f};
      sg1[st] = (f32x4){0.f, 0.f, 0.f, 0.f};
    }
    __builtin_amdgcn_s_setprio(1);
#pragma unroll
    for (int kf = 0; kf < 4; ++kf) {
      int cs = ((kf * 4 + g) ^ l16) << 3;
#pragma unroll
      for (int st = 0; st < 4; ++st) {
        const u16* kp = kb + (st * 16 + l16) * 128 + cs;
        bf16x8 kh = *(const bf16x8*)(const void*)kp;
        bf16x8 kl = *(const bf16x8*)(const void*)(kp + 8192);
        sg0[st] = MFMA(kh, qh0[kf], sg0[st], 0, 0, 0);
        sg0[st] = MFMA(kh, ql0[kf], sg0[st], 0, 0, 0);
        sg0[st] = MFMA(kl, qh0[kf], sg0[st], 0, 0, 0);
        sg1[st] = MFMA(kh, qh1[kf], sg1[st], 0, 0, 0);
        sg1[st] = MFMA(kh, ql1[kf], sg1[st], 0, 0, 0);
        sg1[st] = MFMA(kl, qh1[kf], sg1[st], 0, 0, 0);
      }
    }
    __builtin_amdgcn_s_setprio(0);

    // ---- softmax + P-pack, one chain per group per 64 keys ----
    bf16x8 pa0A, pa0B, pa1A, pa1B;
    SMPACK(sg0, m0, l0, acc0, pa0A, pa0B)
    SMPACK(sg1, m1, l1, acc1, pa1A, pa1B)

    // ---- PV: one V-frag pair feeds both q-groups ----
    __builtin_amdgcn_s_setprio(1);
#pragma unroll
    for (int nf = 0; nf < 8; ++nf) {
      int d = nf * 16 + l16;
      int sw = (d >> 1) & 7;
      const u16* vr = vb + d * 64;
      bf16x8 vf0 = *(const bf16x8*)(const void*)(vr + ((mg ^ sw) << 3));
      bf16x8 vf1 = *(const bf16x8*)(const void*)(vr + (((4 + mg) ^ sw) << 3));
      acc0[nf] = MFMA(pa0A, vf0, acc0[nf], 0, 0, 0);
      acc0[nf] = MFMA(pa0B, vf1, acc0[nf], 0, 0, 0);
      acc1[nf] = MFMA(pa1A, vf0, acc1[nf], 0, 0, 0);
      acc1[nf] = MFMA(pa1B, vf1, acc1[nf], 0, 0, 0);
    }
    __builtin_amdgcn_s_setprio(0);

    cur = (cur + 1 >= 3) ? cur - 2 : cur + 1;
  }

  // ---- write partials (m, l, O) for the 2 16-row groups ----
  const int pidx0 = sp * NQG + (gr0 >> 4);
  {
    u16* po = PO + (size_t)pidx0 * 16 * DIM;
#pragma unroll
    for (int nf = 0; nf < 8; ++nf)
#pragma unroll
      for (int r = 0; r < 4; ++r)
        po[(g * 4 + r) * DIM + nf * 16 + l16] = f2bu(acc0[nf][r]);
    u16* po1 = PO + (size_t)(pidx0 + 1) * 16 * DIM;
#pragma unroll
    for (int nf = 0; nf < 8; ++nf)
#pragma unroll
      for (int r = 0; r < 4; ++r)
        po1[(g * 4 + r) * DIM + nf * 16 + l16] = f2bu(acc1[nf][r]);
  }
  if (g == 0) { Pm[pidx0 * 16 + l16] = m0; Pl[pidx0 * 16 + l16] = l0; }
  if (g == 1) { Pm[(pidx0 + 1) * 16 + l16] = m1; Pl[(pidx0 + 1) * 16 + l16] = l1; }
#undef STAGE
#undef SMPACK
}

// ---------------- kernel 3: combine KV-split partials (wide loads, 256 thr) ----------------
__global__ __launch_bounds__(256) void k_comb(const float* __restrict__ Pm,
                                              const float* __restrict__ Pl,
                                              const u16* __restrict__ PO,
                                              float* __restrict__ out) {
  const int qg = blockIdx.x;
  const int tid = threadIdx.x;

  __shared__ float sc[NSP][16];  // [split][row]
  if (tid < 16) {
    float m = -1e30f;
#pragma unroll
    for (int s = 0; s < NSP; ++s) m = fmaxf(m, Pm[(s * NQG + qg) * 16 + tid]);
    float den = 0.f;
#pragma unroll
    for (int s = 0; s < NSP; ++s) {
      float e = exp2f(Pm[(s * NQG + qg) * 16 + tid] - m);  // log2-domain stats (cold path)
      sc[s][tid] = e;
      den += Pl[(s * NQG + qg) * 16 + tid] * e;
    }
    float inv = 1.0f / den;
#pragma unroll
    for (int s = 0; s < NSP; ++s) sc[s][tid] *= inv;
  }
  __syncthreads();

  // 2048 elems / 256 thr = 8 per thread (one u16x8 per split, two f32x4 stores)
  const int e0 = tid * 8;
  const int row = e0 >> 7;
  float a[8];
#pragma unroll
  for (int j = 0; j < 8; ++j) a[j] = 0.f;
#pragma unroll
  for (int s = 0; s < NSP; ++s) {
    u16x8 p = *(const u16x8*)(const void*)(PO + (size_t)(s * NQG + qg) * 16 * DIM + e0);
    float wgt = sc[s][row];
#pragma unroll
    for (int j = 0; j < 8; ++j) a[j] += bu2f(p[j]) * wgt;
  }
  float* op = out + (size_t)qg * 16 * DIM + e0;
  f32x4 o0 = {a[0], a[1], a[2], a[3]};
  f32x4 o1 = {a[4], a[5], a[6], a[7]};
  *(f32x4*)op = o0;
  *(f32x4*)(op + 4) = o1;
}

extern "C" void kernel_launch(void* const* d_in, const int* in_sizes, int n_in,
                              void* d_out, int out_size, void* d_ws, size_t ws_size,
                              hipStream_t stream) {
  const float* X  = (const float*)d_in[0];
  const float* wq = (const float*)d_in[4];
  const float* wk = (const float*)d_in[5];
  const float* wv = (const float*)d_in[6];
  float* out = (float*)d_out;

  u16* WT = (u16*)d_ws;                       // 3*2*128*128 u16 = 192 KiB
  u16* Qh = WT + 3 * 2 * 128 * 128;
  u16* Ql = Qh + (size_t)BATCH * S_SRC * DIM; // 2 MiB each
  u16* Kh = Ql + (size_t)BATCH * S_SRC * DIM;
  u16* Kl = Kh + (size_t)BATCH * S_SRC * DIM;
  u16* VT = Kl + (size_t)BATCH * S_SRC * DIM; // [B][D][S]
  float* Pm = (float*)(VT + (size_t)BATCH * S_SRC * DIM);  // [NSP*NQG*16] f32
  float* Pl = Pm + (size_t)NSP * NQG * 16;
  u16* PO = (u16*)(Pl + (size_t)NSP * NQG * 16);           // [NSP*NQG*16*128] bf16 = 16 MiB

  hipLaunchKernelGGL(k_wsplit, dim3(192), dim3(256), 0, stream, wq, wk, wv, WT);
  hipLaunchKernelGGL(k_proj, dim3(BATCH * S_SRC / 32), dim3(256), 0, stream,
                     X, WT, Qh, Ql, Kh, Kl, VT);
  hipLaunchKernelGGL(k_attn, dim3(NQB * NSP), dim3(512), 0, stream,
                     Qh, Ql, Kh, Kl, VT, Pm, Pl, PO);
  hipLaunchKernelGGL(k_comb, dim3(NQG), dim3(256), 0, stream, Pm, Pl, PO, out);
}